// Round 12
// baseline (213.469 us; speedup 1.0000x reference)
//
#include <hip/hip_runtime.h>
#include <math.h>

#define T_SEQ 2048
#define C_DIM 1024
#define NHEAD 16
#define HDIM 64
#define M_ROWS 4096   // B*T
#define N_QKV 3072    // 3*C

typedef __attribute__((ext_vector_type(8))) short short8;   // 8 bf16 (4 VGPR)
typedef __attribute__((ext_vector_type(4))) float f32x4;    // MFMA C/D
typedef unsigned short ushort_t;

__device__ inline unsigned short f2bf(float x) {            // RNE f32->bf16
  union { float f; unsigned u; } v; v.f = x;
  unsigned r = v.u + 0x7FFF + ((v.u >> 16) & 1);
  return (unsigned short)(r >> 16);
}
__device__ inline unsigned short f2bf_t(float x) {          // truncating (P only)
  union { float f; unsigned u; } v; v.f = x;
  return (unsigned short)(v.u >> 16);
}
__device__ inline float bf2f(unsigned short h) {
  union { unsigned u; float f; } v; v.u = ((unsigned)h) << 16; return v.f;
}

// async global->LDS, 16B per lane; LDS dest = wave-uniform base + lane*16
__device__ __forceinline__ void gll16(const char* g, char* l) {
  __builtin_amdgcn_global_load_lds(
      (const __attribute__((address_space(1))) unsigned*)g,
      (__attribute__((address_space(3))) unsigned*)l, 16, 0, 0);
}

// ---------------- abs-mean scale (deterministic 2-stage reduction) ----------
__global__ __launch_bounds__(256) void abs_partial_k(const float* __restrict__ w,
                                                     int n, float* __restrict__ part) {
  __shared__ float red[256];
  float s = 0.f;
  for (int i = blockIdx.x * 256 + threadIdx.x; i < n; i += 256 * 256)
    s += fabsf(w[i]);
  red[threadIdx.x] = s;
  __syncthreads();
  for (int st = 128; st > 0; st >>= 1) {
    if ((int)threadIdx.x < st) red[threadIdx.x] += red[threadIdx.x + st];
    __syncthreads();
  }
  if (threadIdx.x == 0) part[blockIdx.x] = red[0];
}

__global__ __launch_bounds__(256) void finalize_scales_k(const float* __restrict__ part,
                                                         float* __restrict__ scales) {
  __shared__ float red[256];
  red[threadIdx.x] = part[blockIdx.x * 256 + threadIdx.x];
  __syncthreads();
  for (int st = 128; st > 0; st >>= 1) {
    if ((int)threadIdx.x < st) red[threadIdx.x] += red[threadIdx.x + st];
    __syncthreads();
  }
  if (threadIdx.x == 0) {
    float n = (blockIdx.x == 0) ? (float)(N_QKV * C_DIM) : (float)(C_DIM * C_DIM);
    scales[blockIdx.x] = fmaxf(red[0] / n, 1e-8f);
  }
}

// ---------------- ternarize -> bf16 (exact: {-1,0,1}) -----------------------
__global__ __launch_bounds__(256) void ternarize_k(const float* __restrict__ w,
                                                   ushort_t* __restrict__ wt, int n,
                                                   const float* __restrict__ scales,
                                                   int which) {
  int i = blockIdx.x * 256 + threadIdx.x;
  if (i < n) {
    float s = scales[which];
    float t = rintf(w[i] / s);           // round-half-even matches jnp.round
    wt[i] = f2bf(fminf(1.f, fmaxf(-1.f, t)));
  }
}

// ---------------- fp32 -> bf16 hi/lo split ----------------------------------
__global__ __launch_bounds__(256) void split_hl_k(const float* __restrict__ in,
                                                  ushort_t* __restrict__ hi,
                                                  ushort_t* __restrict__ lo, int n4) {
  int i = blockIdx.x * 256 + threadIdx.x;
  if (i < n4) {
    const float4 v = ((const float4*)in)[i];
    const float vv[4] = {v.x, v.y, v.z, v.w};
    ushort_t hh[4], ll[4];
#pragma unroll
    for (int j = 0; j < 4; ++j) {
      hh[j] = f2bf(vv[j]);
      ll[j] = f2bf(vv[j] - bf2f(hh[j]));
    }
    ((ushort4*)hi)[i] = make_ushort4(hh[0], hh[1], hh[2], hh[3]);
    ((ushort4*)lo)[i] = make_ushort4(ll[0], ll[1], ll[2], ll[3]);
  }
}

// ---------------- bf16 MFMA GEMM, A split hi/lo (qkv projection) ------------
// 128x128 tile, BK=64, 4 waves 2x2, global_load_lds staging + XOR swizzle.
// V-columns (bn >= 2048) skip the lo-correction pass: V is re-rounded to bf16
// in prep_kv anyway, so the xl term only matters for Q/K score accuracy.
__global__ __launch_bounds__(256) void gemm_bf16_hl(const ushort_t* __restrict__ Ah,
                                                    const ushort_t* __restrict__ Al,
                                                    const ushort_t* __restrict__ Bw,
                                                    float* __restrict__ C,
                                                    int Nd, int Kd) {
  __shared__ __align__(16) char lds[49152];   // Ah 16K | Al 16K | B 16K
  const int tid = threadIdx.x;
  const int bm = blockIdx.y << 7, bn = blockIdx.x << 7;
  const int w = tid >> 6, lane = tid & 63;
  const int wm = (w >> 1) << 6, wn = (w & 1) << 6;
  const int fr = lane & 15, fc = lane >> 4;
  const bool lo_on = (bn < 2048);            // q,k columns need the lo pass

  int srow[4], scol[4];
#pragma unroll
  for (int i = 0; i < 4; ++i) {
    const int slot = i * 256 + tid;
    const int r = slot >> 3, s = slot & 7;
    srow[i] = r;
    scol[i] = (s ^ (r & 7)) << 3;            // pre-swizzled source column
  }

  f32x4 acc[4][4];
  const f32x4 z = {0.f, 0.f, 0.f, 0.f};
#pragma unroll
  for (int i = 0; i < 4; ++i)
#pragma unroll
    for (int j = 0; j < 4; ++j) acc[i][j] = z;

  for (int k0 = 0; k0 < Kd; k0 += 64) {
    __syncthreads();
#pragma unroll
    for (int i = 0; i < 4; ++i) {
      const int d16 = (i * 256 + tid) * 16;
      const size_t ga = (size_t)(bm + srow[i]) * Kd + k0 + scol[i];
      const size_t gb = (size_t)(bn + srow[i]) * Kd + k0 + scol[i];
      gll16((const char*)(Ah + ga), lds + d16);
      if (lo_on) gll16((const char*)(Al + ga), lds + 16384 + d16);
      gll16((const char*)(Bw + gb), lds + 32768 + d16);
    }
    __syncthreads();
#pragma unroll
    for (int ks = 0; ks < 2; ++ks) {
      short8 af[4], lf[4], bf[4];
#pragma unroll
      for (int i = 0; i < 4; ++i) {
        const int ra = wm + i * 16 + fr;
        const int ca = (ks * 64 + fc * 16) ^ ((ra & 7) << 4);
        af[i] = *(const short8*)(lds + ra * 128 + ca);
        if (lo_on) lf[i] = *(const short8*)(lds + 16384 + ra * 128 + ca);
        const int rb = wn + i * 16 + fr;
        const int cbb = (ks * 64 + fc * 16) ^ ((rb & 7) << 4);
        bf[i] = *(const short8*)(lds + 32768 + rb * 128 + cbb);
      }
#pragma unroll
      for (int i = 0; i < 4; ++i)
#pragma unroll
        for (int j = 0; j < 4; ++j) {
          acc[i][j] = __builtin_amdgcn_mfma_f32_16x16x32_bf16(af[i], bf[j], acc[i][j], 0, 0, 0);
          if (lo_on)
            acc[i][j] = __builtin_amdgcn_mfma_f32_16x16x32_bf16(lf[i], bf[j], acc[i][j], 0, 0, 0);
        }
    }
  }
#pragma unroll
  for (int i = 0; i < 4; ++i)
#pragma unroll
    for (int j = 0; j < 4; ++j) {
      float* cp = C + (size_t)(bm + wm + i * 16 + fc * 4) * Nd + bn + wn + j * 16 + fr;
#pragma unroll
      for (int r = 0; r < 4; ++r) cp[(size_t)r * Nd] = acc[i][j][r];
    }
}

// ---------------- bf16 MFMA GEMM, single-pass A (out projection) ------------
__global__ __launch_bounds__(256) void gemm_bf16(const ushort_t* __restrict__ A,
                                                 const ushort_t* __restrict__ Bw,
                                                 float* __restrict__ C,
                                                 int Nd, int Kd) {
  __shared__ __align__(16) char lds[32768];   // A 16K | B 16K
  const int tid = threadIdx.x;
  const int bm = blockIdx.y << 7, bn = blockIdx.x << 7;
  const int w = tid >> 6, lane = tid & 63;
  const int wm = (w >> 1) << 6, wn = (w & 1) << 6;
  const int fr = lane & 15, fc = lane >> 4;

  int srow[4], scol[4];
#pragma unroll
  for (int i = 0; i < 4; ++i) {
    const int slot = i * 256 + tid;
    const int r = slot >> 3, s = slot & 7;
    srow[i] = r;
    scol[i] = (s ^ (r & 7)) << 3;
  }

  f32x4 acc[4][4];
  const f32x4 z = {0.f, 0.f, 0.f, 0.f};
#pragma unroll
  for (int i = 0; i < 4; ++i)
#pragma unroll
    for (int j = 0; j < 4; ++j) acc[i][j] = z;

  for (int k0 = 0; k0 < Kd; k0 += 64) {
    __syncthreads();
#pragma unroll
    for (int i = 0; i < 4; ++i) {
      const int d16 = (i * 256 + tid) * 16;
      gll16((const char*)(A + (size_t)(bm + srow[i]) * Kd + k0 + scol[i]), lds + d16);
      gll16((const char*)(Bw + (size_t)(bn + srow[i]) * Kd + k0 + scol[i]), lds + 16384 + d16);
    }
    __syncthreads();
#pragma unroll
    for (int ks = 0; ks < 2; ++ks) {
      short8 af[4], bf[4];
#pragma unroll
      for (int i = 0; i < 4; ++i) {
        const int ra = wm + i * 16 + fr;
        af[i] = *(const short8*)(lds + ra * 128 + ((ks * 64 + fc * 16) ^ ((ra & 7) << 4)));
        const int rb = wn + i * 16 + fr;
        bf[i] = *(const short8*)(lds + 16384 + rb * 128 + ((ks * 64 + fc * 16) ^ ((rb & 7) << 4)));
      }
#pragma unroll
      for (int i = 0; i < 4; ++i)
#pragma unroll
        for (int j = 0; j < 4; ++j)
          acc[i][j] = __builtin_amdgcn_mfma_f32_16x16x32_bf16(af[i], bf[j], acc[i][j], 0, 0, 0);
    }
  }
#pragma unroll
  for (int i = 0; i < 4; ++i)
#pragma unroll
    for (int j = 0; j < 4; ++j) {
      float* cp = C + (size_t)(bm + wm + i * 16 + fc * 4) * Nd + bn + wn + j * 16 + fr;
#pragma unroll
      for (int r = 0; r < 4; ++r) cp[(size_t)r * Nd] = acc[i][j][r];
    }
}

// ---------------- prep_kv: per-(b,h,chunk) swizzled LDS images --------------
__global__ __launch_bounds__(256) void prep_kv_k(const float* __restrict__ qkv,
                                                 char* __restrict__ img) {
  __shared__ __align__(16) char sm[24576];
  const int tid = threadIdx.x;
  const int c = blockIdx.x & 31, gg = blockIdx.x >> 5;
  const int h = gg & 15, b = gg >> 4;
  const int key = tid >> 2, dg = tid & 3;
  const float* kp = qkv + (size_t)b * T_SEQ * N_QKV +
                    (size_t)(c * 64 + key) * N_QKV + C_DIM + (h << 6) + dg * 16;
  const float4 k0 = *(const float4*)(kp + 0);
  const float4 k1 = *(const float4*)(kp + 4);
  const float4 k2 = *(const float4*)(kp + 8);
  const float4 k3 = *(const float4*)(kp + 12);
  const float4 v0 = *(const float4*)(kp + C_DIM + 0);
  const float4 v1 = *(const float4*)(kp + C_DIM + 4);
  const float4 v2 = *(const float4*)(kp + C_DIM + 8);
  const float4 v3 = *(const float4*)(kp + C_DIM + 12);
  const float kv[16] = {k0.x,k0.y,k0.z,k0.w, k1.x,k1.y,k1.z,k1.w,
                        k2.x,k2.y,k2.z,k2.w, k3.x,k3.y,k3.z,k3.w};
  const float vv[16] = {v0.x,v0.y,v0.z,v0.w, v1.x,v1.y,v1.z,v1.w,
                        v2.x,v2.y,v2.z,v2.w, v3.x,v3.y,v3.z,v3.w};
  short8 khi0, khi1, klo0, klo1;
#pragma unroll
  for (int j = 0; j < 8; ++j) {
    const float x0 = kv[j], x1 = kv[8 + j];
    const unsigned short h0 = f2bf(x0), h1 = f2bf(x1);
    khi0[j] = (short)h0; khi1[j] = (short)h1;
    klo0[j] = (short)f2bf(x0 - bf2f(h0));
    klo1[j] = (short)f2bf(x1 - bf2f(h1));
  }
  const int sw = (key & 7) << 4;
  const int b0 = key * 128 + ((dg * 32) ^ sw);
  const int b1 = key * 128 + ((dg * 32 + 16) ^ sw);
  *(short8*)(sm + b0) = khi0;        *(short8*)(sm + b1) = khi1;
  *(short8*)(sm + 8192 + b0) = klo0; *(short8*)(sm + 8192 + b1) = klo1;
#pragma unroll
  for (int i = 0; i < 16; ++i) {
    const int d = dg * 16 + i;
    *(short*)(sm + 16384 + d * 128 + ((key * 2) ^ ((d & 7) << 4))) = (short)f2bf(vv[i]);
  }
  __syncthreads();
  int4* dst = (int4*)(img + (size_t)blockIdx.x * 24576);
  const int4* src = (const int4*)sm;
#pragma unroll
  for (int i = 0; i < 6; ++i) dst[i * 256 + tid] = src[i * 256 + tid];
}

// ---------------- fused paired-tile MFMA flash attention --------------------
// R11 structure + cheap defer-guard (skip the 16-shfl mc reduce unless some
// value exceeds m+8 -- bit-identical to R11 semantics) + setprio around MFMA
// clusters (2 independently-phased blocks/SIMD -> T5 applies).
struct TS { f32x4 O[4]; float m[4]; float l[4]; };

__device__ __forceinline__ void softmax_core(f32x4* s4, TS& st) {
  // cheap guard: does any value exceed its row's m+8?
  int need = 0;
#pragma unroll
  for (int f = 0; f < 4; ++f)
#pragma unroll
    for (int r = 0; r < 4; ++r)
      need |= (s4[f][r] > st.m[r] + 8.f) ? 1 : 0;
  if (__any(need)) {
    float mc[4];
#pragma unroll
    for (int r = 0; r < 4; ++r)
      mc[r] = fmaxf(fmaxf(s4[0][r], s4[1][r]), fmaxf(s4[2][r], s4[3][r]));
#pragma unroll
    for (int d = 1; d <= 8; d <<= 1)
#pragma unroll
      for (int r = 0; r < 4; ++r) mc[r] = fmaxf(mc[r], __shfl_xor(mc[r], d));
#pragma unroll
    for (int r = 0; r < 4; ++r) {
      const float mn = fmaxf(st.m[r], mc[r]);
      const float resc = __expf(st.m[r] - mn);
      st.m[r] = mn;
      st.l[r] *= resc;
#pragma unroll
      for (int n = 0; n < 4; ++n) st.O[n][r] *= resc;
    }
  }
#pragma unroll
  for (int f = 0; f < 4; ++f)
#pragma unroll
    for (int r = 0; r < 4; ++r)
      s4[f][r] = __expf(s4[f][r] - st.m[r]);
#pragma unroll
  for (int r = 0; r < 4; ++r)
    st.l[r] += (s4[0][r] + s4[1][r]) + (s4[2][r] + s4[3][r]);
}

__device__ __forceinline__ void pv_core(const f32x4* s4, TS& st, char* pp,
                                        const char* vTp, int lg, int lr) {
#pragma unroll
  for (int f = 0; f < 4; ++f)
#pragma unroll
    for (int r = 0; r < 4; ++r) {
      const int q = lg * 4 + r;
      *(short*)(pp + q * 128 + (((lr + 16 * f) * 2) ^ ((q & 7) << 4))) = (short)f2bf_t(s4[f][r]);
    }
  __builtin_amdgcn_s_setprio(1);
#pragma unroll
  for (int s = 0; s < 2; ++s) {
    const int cb = s * 64 + lg * 16;
    const short8 pa = *(const short8*)(pp + lr * 128 + (cb ^ ((lr & 7) << 4)));
#pragma unroll
    for (int n = 0; n < 4; ++n) {
      const int d = lr + 16 * n;
      const short8 vb = *(const short8*)(vTp + d * 128 + (cb ^ ((d & 7) << 4)));
      st.O[n] = __builtin_amdgcn_mfma_f32_16x16x32_bf16(pa, vb, st.O[n], 0, 0, 0);
    }
  }
  __builtin_amdgcn_s_setprio(0);
}

__device__ __forceinline__ void mask_diag(f32x4* s4, int w, int lg, int lr) {
#pragma unroll
  for (int f = 0; f < 4; ++f) {
    const int kg = 16 * f + lr;
#pragma unroll
    for (int r = 0; r < 4; ++r) {
      const int qg = w * 16 + lg * 4 + r;
      if (kg > qg) s4[f][r] = -1e30f;
    }
  }
}

__device__ __forceinline__ void load_q(const float* base, int qt, int h,
                                       int w, int lg, int lr,
                                       short8* qh, short8* ql) {
  const float* qrow = base + (size_t)(qt * 64 + w * 16 + lr) * N_QKV + (h << 6);
#pragma unroll
  for (int s = 0; s < 2; ++s) {
    const float4 a0 = *(const float4*)(qrow + s * 32 + lg * 8);
    const float4 a1 = *(const float4*)(qrow + s * 32 + lg * 8 + 4);
    const float xv[8] = {a0.x, a0.y, a0.z, a0.w, a1.x, a1.y, a1.z, a1.w};
#pragma unroll
    for (int j = 0; j < 8; ++j) {
      const float xs = xv[j] * 0.125f;       // fold 1/sqrt(64)
      const unsigned short hs = f2bf(xs);
      qh[s][j] = (short)hs;
      ql[s][j] = (short)f2bf(xs - bf2f(hs));
    }
  }
}

// store with lane-local l: reduce l across the 16 lr-lanes once here
__device__ __forceinline__ void store_o2(ushort_t* oh, const f32x4* O, float* ll,
                                         int b, int qt, int h,
                                         int w, int lg, int lr) {
#pragma unroll
  for (int d = 1; d <= 8; d <<= 1)
#pragma unroll
    for (int r = 0; r < 4; ++r) ll[r] += __shfl_xor(ll[r], d);
  float inv[4];
#pragma unroll
  for (int r = 0; r < 4; ++r) inv[r] = 1.f / ll[r];
  const size_t ob = (size_t)(b * T_SEQ + qt * 64 + w * 16 + lg * 4) * C_DIM + (h << 6) + lr;
#pragma unroll
  for (int r = 0; r < 4; ++r)
#pragma unroll
    for (int n = 0; n < 4; ++n)
      oh[ob + (size_t)r * C_DIM + 16 * n] = f2bf(O[n][r] * inv[r]);
}

__global__ __launch_bounds__(256) void attn2_k(const float* __restrict__ qkv,
                                               const char* __restrict__ img,
                                               ushort_t* __restrict__ oh) {
  __shared__ __align__(16) char smem[57344];   // buf0 24K | buf1 24K | P 4x2K
  const int tid  = threadIdx.x;
  const int lane = tid & 63;
  const int w    = tid >> 6;
  const int lg   = lane >> 4;
  const int lr   = lane & 15;
  char* const pp = smem + 49152 + (w << 11);

  // gg in low bits -> all 16 p-blocks of one (b,h) land on one XCD (L2-hot img)
  const int bx = blockIdx.x;
  const int p  = (bx >> 3) & 15;
  const int gg = ((bx >> 7) << 3) | (bx & 7);
  const int h  = gg & 15, b = gg >> 4;
  const int qtA = p, qtB = 31 - p;

  const float* base = qkv + (size_t)b * T_SEQ * N_QKV;
  const char* img_gg = img + (size_t)gg * 32 * 24576;

  short8 qhA[2], qlA[2], qhB[2], qlB[2];
  load_q(base, qtA, h, w, lg, lr, qhA, qlA);
  load_q(base, qtB, h, w, lg, lr, qhB, qlB);

  TS stA, stB;
#pragma unroll
  for (int n = 0; n < 4; ++n) {
    const f32x4 z = {0.f, 0.f, 0.f, 0.f};
    stA.O[n] = z; stB.O[n] = z;
    stA.m[n] = -1e30f; stB.m[n] = -1e30f;
    stA.l[n] = 0.f; stB.l[n] = 0.f;
  }

  // prologue: issue chunk 0 into buf0
#pragma unroll
  for (int i = 0; i < 6; ++i)
    gll16(img_gg + i * 4096 + tid * 16, smem + i * 4096 + tid * 16);

  int cur = 0;
  for (int c = 0; c <= qtB; ++c) {
    __syncthreads();                         // drains outstanding loads
    if (c < qtB) {
      const char* src = img_gg + (size_t)(c + 1) * 24576;
      char* dst = smem + (cur ^ 1) * 24576;
#pragma unroll
      for (int i = 0; i < 6; ++i)
        gll16(src + i * 4096 + tid * 16, dst + i * 4096 + tid * 16);
    }
    const char* khp = smem + cur * 24576;
    const char* klp = khp + 8192;
    const char* vTp = khp + 16384;
    const bool actA = (c <= qtA);

    // ---- fused QK: shared K-fragment reads feed both tiles ----
    f32x4 sA[4], sB[4];
    const f32x4 z = {0.f, 0.f, 0.f, 0.f};
#pragma unroll
    for (int f = 0; f < 4; ++f) { sA[f] = z; sB[f] = z; }
    __builtin_amdgcn_s_setprio(1);
#pragma unroll
    for (int s = 0; s < 2; ++s) {
      const int cb = s * 64 + lg * 16;
#pragma unroll
      for (int f = 0; f < 4; ++f) {
        const int row = lr + 16 * f;
        const int byt = row * 128 + (cb ^ ((row & 7) << 4));
        const short8 bh8 = *(const short8*)(khp + byt);
        const short8 bl8 = *(const short8*)(klp + byt);
        sB[f] = __builtin_amdgcn_mfma_f32_16x16x32_bf16(qhB[s], bh8, sB[f], 0, 0, 0);
        sB[f] = __builtin_amdgcn_mfma_f32_16x16x32_bf16(qlB[s], bh8, sB[f], 0, 0, 0);
        sB[f] = __builtin_amdgcn_mfma_f32_16x16x32_bf16(qhB[s], bl8, sB[f], 0, 0, 0);
        if (actA) {
          sA[f] = __builtin_amdgcn_mfma_f32_16x16x32_bf16(qhA[s], bh8, sA[f], 0, 0, 0);
          sA[f] = __builtin_amdgcn_mfma_f32_16x16x32_bf16(qlA[s], bh8, sA[f], 0, 0, 0);
          sA[f] = __builtin_amdgcn_mfma_f32_16x16x32_bf16(qhA[s], bl8, sA[f], 0, 0, 0);
        }
      }
    }
    __builtin_amdgcn_s_setprio(0);
    if (c == qtB) mask_diag(sB, w, lg, lr);
    if (actA && c == qtA) mask_diag(sA, w, lg, lr);

    // ---- two independent softmax chains (ILP) ----
    softmax_core(sB, stB);
    if (actA) softmax_core(sA, stA);

    // ---- PV, shared per-wave P buffer (same-wave DS order => WAR safe) ----
    pv_core(sB, stB, pp, vTp, lg, lr);
    if (actA) pv_core(sA, stA, pp, vTp, lg, lr);

    cur ^= 1;
  }

  store_o2(oh, stA.O, stA.l, b, qtA, h, w, lg, lr);
  store_o2(oh, stB.O, stB.l, b, qtB, h, w, lg, lr);
}

// ---------------- launch ----------------------------------------------------
extern "C" void kernel_launch(void* const* d_in, const int* in_sizes, int n_in,
                              void* d_out, int out_size, void* d_ws, size_t ws_size,
                              hipStream_t stream) {
  const float* x      = (const float*)d_in[0];   // [4096][1024]
  const float* w_qkv  = (const float*)d_in[1];   // [3072][1024]
  const float* w_out  = (const float*)d_in[2];   // [1024][1024]
  float* out = (float*)d_out;                    // [4096][1024]

  // layout (img aliases wt_qkv, which is dead after gemm1; stream-ordered)
  char* pch = (char*)d_ws;
  ushort_t* wt_out = (ushort_t*)pch;  pch += (size_t)C_DIM * C_DIM * 2;    // 2MB
  ushort_t* xh     = (ushort_t*)pch;  pch += (size_t)M_ROWS * C_DIM * 2;   // 8MB
  ushort_t* xl     = (ushort_t*)pch;  pch += (size_t)M_ROWS * C_DIM * 2;   // 8MB
  float*    qkv    = (float*)pch;     pch += (size_t)M_ROWS * N_QKV * 4;   // 48MB
  ushort_t* wt_qkv = (ushort_t*)pch;                                       // 6MB..
  char*     img    = pch;             pch += (size_t)1024 * 24576;         // 25.2MB
  float*    part   = (float*)pch;     pch += 512 * 4;
  float*    scales = (float*)pch;
  ushort_t* ah = xh;   // x hi dead after gemm1 -> attn output

  hipLaunchKernelGGL(abs_partial_k, dim3(256), dim3(256), 0, stream,
                     w_qkv, N_QKV * C_DIM, part);
  hipLaunchKernelGGL(abs_partial_k, dim3(256), dim3(256), 0, stream,
                     w_out, C_DIM * C_DIM, part + 256);
  hipLaunchKernelGGL(finalize_scales_k, dim3(2), dim3(256), 0, stream, part, scales);

  hipLaunchKernelGGL(ternarize_k, dim3((N_QKV * C_DIM) / 256), dim3(256), 0, stream,
                     w_qkv, wt_qkv, N_QKV * C_DIM, scales, 0);
  hipLaunchKernelGGL(ternarize_k, dim3((C_DIM * C_DIM) / 256), dim3(256), 0, stream,
                     w_out, wt_out, C_DIM * C_DIM, scales, 1);

  hipLaunchKernelGGL(split_hl_k, dim3((M_ROWS * C_DIM / 4) / 256), dim3(256), 0, stream,
                     x, xh, xl, M_ROWS * C_DIM / 4);

  // qkv = (xh+xl) @ wt_qkv^T  (lo pass skipped for V columns)
  hipLaunchKernelGGL(gemm_bf16_hl, dim3(N_QKV / 128, M_ROWS / 128), dim3(256), 0, stream,
                     xh, xl, wt_qkv, qkv, N_QKV, C_DIM);

  // K/V chunk images (overwrites wt_qkv region — dead now)
  hipLaunchKernelGGL(prep_kv_k, dim3(1024), dim3(256), 0, stream, qkv, img);

  // attention -> bf16
  hipLaunchKernelGGL(attn2_k, dim3(512), dim3(256), 0, stream, qkv, img, ah);

  // out = ah @ wt_out^T
  hipLaunchKernelGGL(gemm_bf16, dim3(C_DIM / 128, M_ROWS / 128), dim3(256), 0, stream,
                     ah, wt_out, out, C_DIM, C_DIM);
}

// Round 13
// 193.935 us; speedup vs baseline: 1.1007x; 1.1007x over previous
//
#include <hip/hip_runtime.h>
#include <math.h>

#define T_SEQ 2048
#define C_DIM 1024
#define NHEAD 16
#define HDIM 64
#define M_ROWS 4096   // B*T
#define N_QKV 3072    // 3*C

typedef __attribute__((ext_vector_type(8))) short short8;   // 8 bf16 (4 VGPR)
typedef __attribute__((ext_vector_type(4))) float f32x4;    // MFMA C/D
typedef unsigned short ushort_t;

__device__ inline unsigned short f2bf(float x) {            // RNE f32->bf16
  union { float f; unsigned u; } v; v.f = x;
  unsigned r = v.u + 0x7FFF + ((v.u >> 16) & 1);
  return (unsigned short)(r >> 16);
}
__device__ inline float bf2f(unsigned short h) {
  union { unsigned u; float f; } v; v.u = ((unsigned)h) << 16; return v.f;
}
__device__ inline unsigned fbits(float x) {
  union { float f; unsigned u; } v; v.f = x; return v.u;
}

// async global->LDS, 16B per lane; LDS dest = wave-uniform base + lane*16
__device__ __forceinline__ void gll16(const char* g, char* l) {
  __builtin_amdgcn_global_load_lds(
      (const __attribute__((address_space(1))) unsigned*)g,
      (__attribute__((address_space(3))) unsigned*)l, 16, 0, 0);
}

// ---------------- abs-mean scale (deterministic 2-stage reduction) ----------
__global__ __launch_bounds__(256) void abs_partial_k(const float* __restrict__ w,
                                                     int n, float* __restrict__ part) {
  __shared__ float red[256];
  float s = 0.f;
  for (int i = blockIdx.x * 256 + threadIdx.x; i < n; i += 256 * 256)
    s += fabsf(w[i]);
  red[threadIdx.x] = s;
  __syncthreads();
  for (int st = 128; st > 0; st >>= 1) {
    if ((int)threadIdx.x < st) red[threadIdx.x] += red[threadIdx.x + st];
    __syncthreads();
  }
  if (threadIdx.x == 0) part[blockIdx.x] = red[0];
}

__global__ __launch_bounds__(256) void finalize_scales_k(const float* __restrict__ part,
                                                         float* __restrict__ scales) {
  __shared__ float red[256];
  red[threadIdx.x] = part[blockIdx.x * 256 + threadIdx.x];
  __syncthreads();
  for (int st = 128; st > 0; st >>= 1) {
    if ((int)threadIdx.x < st) red[threadIdx.x] += red[threadIdx.x + st];
    __syncthreads();
  }
  if (threadIdx.x == 0) {
    float n = (blockIdx.x == 0) ? (float)(N_QKV * C_DIM) : (float)(C_DIM * C_DIM);
    scales[blockIdx.x] = fmaxf(red[0] / n, 1e-8f);
  }
}

// ---------------- ternarize -> bf16 (exact: {-1,0,1}) -----------------------
__global__ __launch_bounds__(256) void ternarize_k(const float* __restrict__ w,
                                                   ushort_t* __restrict__ wt, int n,
                                                   const float* __restrict__ scales,
                                                   int which) {
  int i = blockIdx.x * 256 + threadIdx.x;
  if (i < n) {
    float s = scales[which];
    float t = rintf(w[i] / s);           // round-half-even matches jnp.round
    wt[i] = f2bf(fminf(1.f, fmaxf(-1.f, t)));
  }
}

// ---------------- fp32 -> bf16 hi/lo split ----------------------------------
__global__ __launch_bounds__(256) void split_hl_k(const float* __restrict__ in,
                                                  ushort_t* __restrict__ hi,
                                                  ushort_t* __restrict__ lo, int n4) {
  int i = blockIdx.x * 256 + threadIdx.x;
  if (i < n4) {
    const float4 v = ((const float4*)in)[i];
    const float vv[4] = {v.x, v.y, v.z, v.w};
    ushort_t hh[4], ll[4];
#pragma unroll
    for (int j = 0; j < 4; ++j) {
      hh[j] = f2bf(vv[j]);
      ll[j] = f2bf(vv[j] - bf2f(hh[j]));
    }
    ((ushort4*)hi)[i] = make_ushort4(hh[0], hh[1], hh[2], hh[3]);
    ((ushort4*)lo)[i] = make_ushort4(ll[0], ll[1], ll[2], ll[3]);
  }
}

// ---------------- bf16 MFMA GEMM, A split hi/lo (qkv projection) ------------
__global__ __launch_bounds__(256) void gemm_bf16_hl(const ushort_t* __restrict__ Ah,
                                                    const ushort_t* __restrict__ Al,
                                                    const ushort_t* __restrict__ Bw,
                                                    float* __restrict__ C,
                                                    int Nd, int Kd) {
  __shared__ __align__(16) char lds[49152];   // Ah 16K | Al 16K | B 16K
  const int tid = threadIdx.x;
  const int bm = blockIdx.y << 7, bn = blockIdx.x << 7;
  const int w = tid >> 6, lane = tid & 63;
  const int wm = (w >> 1) << 6, wn = (w & 1) << 6;
  const int fr = lane & 15, fc = lane >> 4;

  int srow[4], scol[4];
#pragma unroll
  for (int i = 0; i < 4; ++i) {
    const int slot = i * 256 + tid;
    const int r = slot >> 3, s = slot & 7;
    srow[i] = r;
    scol[i] = (s ^ (r & 7)) << 3;            // pre-swizzled source column
  }

  f32x4 acc[4][4];
  const f32x4 z = {0.f, 0.f, 0.f, 0.f};
#pragma unroll
  for (int i = 0; i < 4; ++i)
#pragma unroll
    for (int j = 0; j < 4; ++j) acc[i][j] = z;

  for (int k0 = 0; k0 < Kd; k0 += 64) {
    __syncthreads();
#pragma unroll
    for (int i = 0; i < 4; ++i) {
      const int d16 = (i * 256 + tid) * 16;
      const size_t ga = (size_t)(bm + srow[i]) * Kd + k0 + scol[i];
      const size_t gb = (size_t)(bn + srow[i]) * Kd + k0 + scol[i];
      gll16((const char*)(Ah + ga), lds + d16);
      gll16((const char*)(Al + ga), lds + 16384 + d16);
      gll16((const char*)(Bw + gb), lds + 32768 + d16);
    }
    __syncthreads();
#pragma unroll
    for (int ks = 0; ks < 2; ++ks) {
      short8 af[4], lf[4], bf[4];
#pragma unroll
      for (int i = 0; i < 4; ++i) {
        const int ra = wm + i * 16 + fr;
        const int ca = (ks * 64 + fc * 16) ^ ((ra & 7) << 4);
        af[i] = *(const short8*)(lds + ra * 128 + ca);
        lf[i] = *(const short8*)(lds + 16384 + ra * 128 + ca);
        const int rb = wn + i * 16 + fr;
        const int cbb = (ks * 64 + fc * 16) ^ ((rb & 7) << 4);
        bf[i] = *(const short8*)(lds + 32768 + rb * 128 + cbb);
      }
#pragma unroll
      for (int i = 0; i < 4; ++i)
#pragma unroll
        for (int j = 0; j < 4; ++j) {
          acc[i][j] = __builtin_amdgcn_mfma_f32_16x16x32_bf16(af[i], bf[j], acc[i][j], 0, 0, 0);
          acc[i][j] = __builtin_amdgcn_mfma_f32_16x16x32_bf16(lf[i], bf[j], acc[i][j], 0, 0, 0);
        }
    }
  }
#pragma unroll
  for (int i = 0; i < 4; ++i)
#pragma unroll
    for (int j = 0; j < 4; ++j) {
      float* cp = C + (size_t)(bm + wm + i * 16 + fc * 4) * Nd + bn + wn + j * 16 + fr;
#pragma unroll
      for (int r = 0; r < 4; ++r) cp[(size_t)r * Nd] = acc[i][j][r];
    }
}

// ---------------- bf16 MFMA GEMM, single-pass A (out projection) ------------
__global__ __launch_bounds__(256) void gemm_bf16(const ushort_t* __restrict__ A,
                                                 const ushort_t* __restrict__ Bw,
                                                 float* __restrict__ C,
                                                 int Nd, int Kd) {
  __shared__ __align__(16) char lds[32768];   // A 16K | B 16K
  const int tid = threadIdx.x;
  const int bm = blockIdx.y << 7, bn = blockIdx.x << 7;
  const int w = tid >> 6, lane = tid & 63;
  const int wm = (w >> 1) << 6, wn = (w & 1) << 6;
  const int fr = lane & 15, fc = lane >> 4;

  int srow[4], scol[4];
#pragma unroll
  for (int i = 0; i < 4; ++i) {
    const int slot = i * 256 + tid;
    const int r = slot >> 3, s = slot & 7;
    srow[i] = r;
    scol[i] = (s ^ (r & 7)) << 3;
  }

  f32x4 acc[4][4];
  const f32x4 z = {0.f, 0.f, 0.f, 0.f};
#pragma unroll
  for (int i = 0; i < 4; ++i)
#pragma unroll
    for (int j = 0; j < 4; ++j) acc[i][j] = z;

  for (int k0 = 0; k0 < Kd; k0 += 64) {
    __syncthreads();
#pragma unroll
    for (int i = 0; i < 4; ++i) {
      const int d16 = (i * 256 + tid) * 16;
      gll16((const char*)(A + (size_t)(bm + srow[i]) * Kd + k0 + scol[i]), lds + d16);
      gll16((const char*)(Bw + (size_t)(bn + srow[i]) * Kd + k0 + scol[i]), lds + 16384 + d16);
    }
    __syncthreads();
#pragma unroll
    for (int ks = 0; ks < 2; ++ks) {
      short8 af[4], bf[4];
#pragma unroll
      for (int i = 0; i < 4; ++i) {
        const int ra = wm + i * 16 + fr;
        af[i] = *(const short8*)(lds + ra * 128 + ((ks * 64 + fc * 16) ^ ((ra & 7) << 4)));
        const int rb = wn + i * 16 + fr;
        bf[i] = *(const short8*)(lds + 16384 + rb * 128 + ((ks * 64 + fc * 16) ^ ((rb & 7) << 4)));
      }
#pragma unroll
      for (int i = 0; i < 4; ++i)
#pragma unroll
        for (int j = 0; j < 4; ++j)
          acc[i][j] = __builtin_amdgcn_mfma_f32_16x16x32_bf16(af[i], bf[j], acc[i][j], 0, 0, 0);
    }
  }
#pragma unroll
  for (int i = 0; i < 4; ++i)
#pragma unroll
    for (int j = 0; j < 4; ++j) {
      float* cp = C + (size_t)(bm + wm + i * 16 + fc * 4) * Nd + bn + wn + j * 16 + fr;
#pragma unroll
      for (int r = 0; r < 4; ++r) cp[(size_t)r * Nd] = acc[i][j][r];
    }
}

// ---------------- prep_kv: per-(b,h,chunk) swizzled LDS images --------------
__global__ __launch_bounds__(256) void prep_kv_k(const float* __restrict__ qkv,
                                                 char* __restrict__ img) {
  __shared__ __align__(16) char sm[24576];
  const int tid = threadIdx.x;
  const int c = blockIdx.x & 31, gg = blockIdx.x >> 5;
  const int h = gg & 15, b = gg >> 4;
  const int key = tid >> 2, dg = tid & 3;
  const float* kp = qkv + (size_t)b * T_SEQ * N_QKV +
                    (size_t)(c * 64 + key) * N_QKV + C_DIM + (h << 6) + dg * 16;
  const float4 k0 = *(const float4*)(kp + 0);
  const float4 k1 = *(const float4*)(kp + 4);
  const float4 k2 = *(const float4*)(kp + 8);
  const float4 k3 = *(const float4*)(kp + 12);
  const float4 v0 = *(const float4*)(kp + C_DIM + 0);
  const float4 v1 = *(const float4*)(kp + C_DIM + 4);
  const float4 v2 = *(const float4*)(kp + C_DIM + 8);
  const float4 v3 = *(const float4*)(kp + C_DIM + 12);
  const float kv[16] = {k0.x,k0.y,k0.z,k0.w, k1.x,k1.y,k1.z,k1.w,
                        k2.x,k2.y,k2.z,k2.w, k3.x,k3.y,k3.z,k3.w};
  const float vv[16] = {v0.x,v0.y,v0.z,v0.w, v1.x,v1.y,v1.z,v1.w,
                        v2.x,v2.y,v2.z,v2.w, v3.x,v3.y,v3.z,v3.w};
  short8 khi0, khi1, klo0, klo1;
#pragma unroll
  for (int j = 0; j < 8; ++j) {
    const float x0 = kv[j], x1 = kv[8 + j];
    const unsigned short h0 = f2bf(x0), h1 = f2bf(x1);
    khi0[j] = (short)h0; khi1[j] = (short)h1;
    klo0[j] = (short)f2bf(x0 - bf2f(h0));
    klo1[j] = (short)f2bf(x1 - bf2f(h1));
  }
  const int sw = (key & 7) << 4;
  const int b0 = key * 128 + ((dg * 32) ^ sw);
  const int b1 = key * 128 + ((dg * 32 + 16) ^ sw);
  *(short8*)(sm + b0) = khi0;        *(short8*)(sm + b1) = khi1;
  *(short8*)(sm + 8192 + b0) = klo0; *(short8*)(sm + 8192 + b1) = klo1;
#pragma unroll
  for (int i = 0; i < 16; ++i) {
    const int d = dg * 16 + i;
    *(short*)(sm + 16384 + d * 128 + ((key * 2) ^ ((d & 7) << 4))) = (short)f2bf(vv[i]);
  }
  __syncthreads();
  int4* dst = (int4*)(img + (size_t)blockIdx.x * 24576);
  const int4* src = (const int4*)sm;
#pragma unroll
  for (int i = 0; i < 6; ++i) dst[i * 256 + tid] = src[i * 256 + tid];
}

// ---------------- swapped-QK paired-tile MFMA flash attention ---------------
// S^T = mfma(K_frag, Q_frag): identical LDS reads, but each lane holds 16
// key-scores for ONE query (q=lr, key=16f+4lg+r). Softmax state is scalar
// m,l per thread; P goes to PV fully in-register (pack + 16 shfl gather into
// B-operand order), eliminating the P-LDS round-trip. exp2 domain (log2e
// folded into Q scale). Defer-max THR=11.5 (= 8 nats, validated bound).
struct TS2 { f32x4 O[4]; float m; float l; };

__device__ __forceinline__ void post_qk(f32x4* s4, TS2& st, const char* vTp,
                                        const bool diag, const int w, const int lg,
                                        const int lr, const int sh0, const int sh1) {
  if (diag) {
#pragma unroll
    for (int f = 0; f < 4; ++f)
#pragma unroll
      for (int r = 0; r < 4; ++r)
        if (16 * f + 4 * lg + r > w * 16 + lr) s4[f][r] = -1e30f;
  }
  float mc = fmaxf(fmaxf(s4[0][0], s4[0][1]), fmaxf(s4[0][2], s4[0][3]));
#pragma unroll
  for (int f = 1; f < 4; ++f)
#pragma unroll
    for (int r = 0; r < 4; ++r) mc = fmaxf(mc, s4[f][r]);
  if (__any(mc > st.m + 11.5f)) {          // defer-max (log2 units)
    mc = fmaxf(mc, __shfl_xor(mc, 16));    // group max over lg (keeps m
    mc = fmaxf(mc, __shfl_xor(mc, 32));    //  consistent across the 4 lanes)
    const float mn = fmaxf(st.m, mc);
    const float rs = exp2f(st.m - mn);
    st.m = mn;
    st.l *= rs;
#pragma unroll
    for (int n = 0; n < 4; ++n)
#pragma unroll
      for (int r = 0; r < 4; ++r) st.O[n][r] *= rs;
  }
#pragma unroll
  for (int f = 0; f < 4; ++f)
#pragma unroll
    for (int r = 0; r < 4; ++r) s4[f][r] = exp2f(s4[f][r] - st.m);
#pragma unroll
  for (int f = 0; f < 4; ++f)
    st.l += (s4[f][0] + s4[f][1]) + (s4[f][2] + s4[f][3]);

  // pack adjacent key-pairs: D[f][rp] = bf16(p[2rp]) | bf16(p[2rp+1])<<16
  unsigned D[4][2];
#pragma unroll
  for (int f = 0; f < 4; ++f)
#pragma unroll
    for (int rp = 0; rp < 2; ++rp)
      D[f][rp] = (fbits(s4[f][2 * rp + 1]) & 0xFFFF0000u) | (fbits(s4[f][2 * rp]) >> 16);

  // gather group's P into B-operand order: slot(s,t) = D[2s+(lg>>1)][t&1]
  // from lane lr+32(lg&1)+16(t>>1)
  int g[4][2][2];
#pragma unroll
  for (int f = 0; f < 4; ++f)
#pragma unroll
    for (int rp = 0; rp < 2; ++rp) {
      g[f][rp][0] = __shfl((int)D[f][rp], sh0, 64);
      g[f][rp][1] = __shfl((int)D[f][rp], sh1, 64);
    }
  const bool hi2 = (lg & 2) != 0;
  union PB { int4 i; short8 s; } pb0, pb1;
  pb0.i.x = hi2 ? g[1][0][0] : g[0][0][0];
  pb0.i.y = hi2 ? g[1][1][0] : g[0][1][0];
  pb0.i.z = hi2 ? g[1][0][1] : g[0][0][1];
  pb0.i.w = hi2 ? g[1][1][1] : g[0][1][1];
  pb1.i.x = hi2 ? g[3][0][0] : g[2][0][0];
  pb1.i.y = hi2 ? g[3][1][0] : g[2][1][0];
  pb1.i.z = hi2 ? g[3][0][1] : g[2][0][1];
  pb1.i.w = hi2 ? g[3][1][1] : g[2][1][1];

  // PV: O^T[d][q] = mfma(A=V^T rows 16n+lr, B=P^T); V^T reads unchanged
  const int swz = (lr & 7) << 4;
#pragma unroll
  for (int n = 0; n < 4; ++n) {
    const int d = 16 * n + lr;
    const short8 va0 = *(const short8*)(vTp + d * 128 + ((lg * 16) ^ swz));
    st.O[n] = __builtin_amdgcn_mfma_f32_16x16x32_bf16(va0, pb0.s, st.O[n], 0, 0, 0);
    const short8 va1 = *(const short8*)(vTp + d * 128 + ((64 + lg * 16) ^ swz));
    st.O[n] = __builtin_amdgcn_mfma_f32_16x16x32_bf16(va1, pb1.s, st.O[n], 0, 0, 0);
  }
}

__device__ __forceinline__ void load_q(const float* base, int qt, int h,
                                       int w, int lg, int lr,
                                       short8* qh, short8* ql) {
  const float* qrow = base + (size_t)(qt * 64 + w * 16 + lr) * N_QKV + (h << 6);
#pragma unroll
  for (int s = 0; s < 2; ++s) {
    const float4 a0 = *(const float4*)(qrow + s * 32 + lg * 8);
    const float4 a1 = *(const float4*)(qrow + s * 32 + lg * 8 + 4);
    const float xv[8] = {a0.x, a0.y, a0.z, a0.w, a1.x, a1.y, a1.z, a1.w};
#pragma unroll
    for (int j = 0; j < 8; ++j) {
      const float xs = xv[j] * 0.1803368801f;   // (1/8) * log2(e): exp2 domain
      const unsigned short hs = f2bf(xs);
      qh[s][j] = (short)hs;
      ql[s][j] = (short)f2bf(xs - bf2f(hs));
    }
  }
}

__device__ __forceinline__ void store_o3(ushort_t* oh, TS2& st,
                                         int b, int qt, int h,
                                         int w, int lg, int lr) {
  float l = st.l;                          // lane-local partial (16 keys)
  l += __shfl_xor(l, 16);                  // sum over the 4-lane group
  l += __shfl_xor(l, 32);
  const float inv = 1.f / l;
  ushort_t* orow = oh + (size_t)(b * T_SEQ + qt * 64 + w * 16 + lr) * C_DIM
                   + (h << 6) + (lg << 2);
#pragma unroll
  for (int n = 0; n < 4; ++n) {
    ushort4 o;
    o.x = f2bf(st.O[n][0] * inv);
    o.y = f2bf(st.O[n][1] * inv);
    o.z = f2bf(st.O[n][2] * inv);
    o.w = f2bf(st.O[n][3] * inv);
    *(ushort4*)(orow + 16 * n) = o;        // d = 16n + 4lg + r
  }
}

__global__ __launch_bounds__(256) void attn2_k(const float* __restrict__ qkv,
                                               const char* __restrict__ img,
                                               ushort_t* __restrict__ oh) {
  __shared__ __align__(16) char smem[49152];   // buf0 24K | buf1 24K (no P!)
  const int tid  = threadIdx.x;
  const int lane = tid & 63;
  const int w    = tid >> 6;
  const int lg   = lane >> 4;
  const int lr   = lane & 15;
  const int sh0  = lr + 32 * (lg & 1);     // P-gather source lanes
  const int sh1  = sh0 + 16;

  // gg in low bits -> all 16 p-blocks of one (b,h) land on one XCD (L2-hot img)
  const int bx = blockIdx.x;
  const int p  = (bx >> 3) & 15;
  const int gg = ((bx >> 7) << 3) | (bx & 7);
  const int h  = gg & 15, b = gg >> 4;
  const int qtA = p, qtB = 31 - p;

  const float* base = qkv + (size_t)b * T_SEQ * N_QKV;
  const char* img_gg = img + (size_t)gg * 32 * 24576;

  short8 qhA[2], qlA[2], qhB[2], qlB[2];
  load_q(base, qtA, h, w, lg, lr, qhA, qlA);
  load_q(base, qtB, h, w, lg, lr, qhB, qlB);

  TS2 stA, stB;
#pragma unroll
  for (int n = 0; n < 4; ++n) {
    const f32x4 z = {0.f, 0.f, 0.f, 0.f};
    stA.O[n] = z; stB.O[n] = z;
  }
  stA.m = -1e30f; stB.m = -1e30f;
  stA.l = 0.f; stB.l = 0.f;

  // prologue: issue chunk 0 into buf0
#pragma unroll
  for (int i = 0; i < 6; ++i)
    gll16(img_gg + i * 4096 + tid * 16, smem + i * 4096 + tid * 16);

  int cur = 0;
  for (int c = 0; c <= qtB; ++c) {
    __syncthreads();                         // drains outstanding loads
    if (c < qtB) {
      const char* src = img_gg + (size_t)(c + 1) * 24576;
      char* dst = smem + (cur ^ 1) * 24576;
#pragma unroll
      for (int i = 0; i < 6; ++i)
        gll16(src + i * 4096 + tid * 16, dst + i * 4096 + tid * 16);
    }
    const char* khp = smem + cur * 24576;
    const char* klp = khp + 8192;
    const char* vTp = khp + 16384;
    const bool actA = (c <= qtA);

    // ---- fused swapped QK: shared K-fragment reads feed both tiles ----
    f32x4 sA[4], sB[4];
    const f32x4 z = {0.f, 0.f, 0.f, 0.f};
#pragma unroll
    for (int f = 0; f < 4; ++f) { sA[f] = z; sB[f] = z; }
#pragma unroll
    for (int s = 0; s < 2; ++s) {
      const int cb = s * 64 + lg * 16;
#pragma unroll
      for (int f = 0; f < 4; ++f) {
        const int row = lr + 16 * f;
        const int byt = row * 128 + (cb ^ ((row & 7) << 4));
        const short8 kh8 = *(const short8*)(khp + byt);
        const short8 kl8 = *(const short8*)(klp + byt);
        sB[f] = __builtin_amdgcn_mfma_f32_16x16x32_bf16(kh8, qhB[s], sB[f], 0, 0, 0);
        sB[f] = __builtin_amdgcn_mfma_f32_16x16x32_bf16(kh8, qlB[s], sB[f], 0, 0, 0);
        sB[f] = __builtin_amdgcn_mfma_f32_16x16x32_bf16(kl8, qhB[s], sB[f], 0, 0, 0);
        if (actA) {
          sA[f] = __builtin_amdgcn_mfma_f32_16x16x32_bf16(kh8, qhA[s], sA[f], 0, 0, 0);
          sA[f] = __builtin_amdgcn_mfma_f32_16x16x32_bf16(kh8, qlA[s], sA[f], 0, 0, 0);
          sA[f] = __builtin_amdgcn_mfma_f32_16x16x32_bf16(kl8, qhA[s], sA[f], 0, 0, 0);
        }
      }
    }
    post_qk(sB, stB, vTp, c == qtB, w, lg, lr, sh0, sh1);
    if (actA) post_qk(sA, stA, vTp, c == qtA, w, lg, lr, sh0, sh1);

    cur ^= 1;
  }

  store_o3(oh, stA, b, qtA, h, w, lg, lr);
  store_o3(oh, stB, b, qtB, h, w, lg, lr);
}

// ---------------- launch ----------------------------------------------------
extern "C" void kernel_launch(void* const* d_in, const int* in_sizes, int n_in,
                              void* d_out, int out_size, void* d_ws, size_t ws_size,
                              hipStream_t stream) {
  const float* x      = (const float*)d_in[0];   // [4096][1024]
  const float* w_qkv  = (const float*)d_in[1];   // [3072][1024]
  const float* w_out  = (const float*)d_in[2];   // [1024][1024]
  float* out = (float*)d_out;                    // [4096][1024]

  // layout (img aliases wt_qkv, which is dead after gemm1; stream-ordered)
  char* pch = (char*)d_ws;
  ushort_t* wt_out = (ushort_t*)pch;  pch += (size_t)C_DIM * C_DIM * 2;    // 2MB
  ushort_t* xh     = (ushort_t*)pch;  pch += (size_t)M_ROWS * C_DIM * 2;   // 8MB
  ushort_t* xl     = (ushort_t*)pch;  pch += (size_t)M_ROWS * C_DIM * 2;   // 8MB
  float*    qkv    = (float*)pch;     pch += (size_t)M_ROWS * N_QKV * 4;   // 48MB
  ushort_t* wt_qkv = (ushort_t*)pch;                                       // 6MB..
  char*     img    = pch;             pch += (size_t)1024 * 24576;         // 25.2MB
  float*    part   = (float*)pch;     pch += 512 * 4;
  float*    scales = (float*)pch;
  ushort_t* ah = xh;   // x hi dead after gemm1 -> attn output

  hipLaunchKernelGGL(abs_partial_k, dim3(256), dim3(256), 0, stream,
                     w_qkv, N_QKV * C_DIM, part);
  hipLaunchKernelGGL(abs_partial_k, dim3(256), dim3(256), 0, stream,
                     w_out, C_DIM * C_DIM, part + 256);
  hipLaunchKernelGGL(finalize_scales_k, dim3(2), dim3(256), 0, stream, part, scales);

  hipLaunchKernelGGL(ternarize_k, dim3((N_QKV * C_DIM) / 256), dim3(256), 0, stream,
                     w_qkv, wt_qkv, N_QKV * C_DIM, scales, 0);
  hipLaunchKernelGGL(ternarize_k, dim3((C_DIM * C_DIM) / 256), dim3(256), 0, stream,
                     w_out, wt_out, C_DIM * C_DIM, scales, 1);

  hipLaunchKernelGGL(split_hl_k, dim3((M_ROWS * C_DIM / 4) / 256), dim3(256), 0, stream,
                     x, xh, xl, M_ROWS * C_DIM / 4);

  // qkv = (xh+xl) @ wt_qkv^T
  hipLaunchKernelGGL(gemm_bf16_hl, dim3(N_QKV / 128, M_ROWS / 128), dim3(256), 0, stream,
                     xh, xl, wt_qkv, qkv, N_QKV, C_DIM);

  // K/V chunk images (overwrites wt_qkv region — dead now)
  hipLaunchKernelGGL(prep_kv_k, dim3(1024), dim3(256), 0, stream, qkv, img);

  // attention -> bf16
  hipLaunchKernelGGL(attn2_k, dim3(512), dim3(256), 0, stream, qkv, img, ah);

  // out = ah @ wt_out^T
  hipLaunchKernelGGL(gemm_bf16, dim3(C_DIM / 128, M_ROWS / 128), dim3(256), 0, stream,
                     ah, wt_out, out, C_DIM, C_DIM);
}

// Round 14
// 188.866 us; speedup vs baseline: 1.1303x; 1.0268x over previous
//
#include <hip/hip_runtime.h>
#include <math.h>

#define T_SEQ 2048
#define C_DIM 1024
#define NHEAD 16
#define HDIM 64
#define M_ROWS 4096   // B*T
#define N_QKV 3072    // 3*C

typedef __attribute__((ext_vector_type(8))) short short8;   // 8 bf16 (4 VGPR)
typedef __attribute__((ext_vector_type(4))) float f32x4;    // MFMA C/D
typedef unsigned short ushort_t;

__device__ inline unsigned short f2bf(float x) {            // RNE f32->bf16
  union { float f; unsigned u; } v; v.f = x;
  unsigned r = v.u + 0x7FFF + ((v.u >> 16) & 1);
  return (unsigned short)(r >> 16);
}
__device__ inline float bf2f(unsigned short h) {
  union { unsigned u; float f; } v; v.u = ((unsigned)h) << 16; return v.f;
}
__device__ inline unsigned fbits(float x) {
  union { float f; unsigned u; } v; v.f = x; return v.u;
}

// async global->LDS, 16B per lane; LDS dest = wave-uniform base + lane*16
__device__ __forceinline__ void gll16(const char* g, char* l) {
  __builtin_amdgcn_global_load_lds(
      (const __attribute__((address_space(1))) unsigned*)g,
      (__attribute__((address_space(3))) unsigned*)l, 16, 0, 0);
}

// ---------------- abs-mean scale (deterministic 2-stage reduction) ----------
__global__ __launch_bounds__(256) void abs_partial_k(const float* __restrict__ w,
                                                     int n, float* __restrict__ part) {
  __shared__ float red[256];
  float s = 0.f;
  for (int i = blockIdx.x * 256 + threadIdx.x; i < n; i += 256 * 256)
    s += fabsf(w[i]);
  red[threadIdx.x] = s;
  __syncthreads();
  for (int st = 128; st > 0; st >>= 1) {
    if ((int)threadIdx.x < st) red[threadIdx.x] += red[threadIdx.x + st];
    __syncthreads();
  }
  if (threadIdx.x == 0) part[blockIdx.x] = red[0];
}

__global__ __launch_bounds__(256) void finalize_scales_k(const float* __restrict__ part,
                                                         float* __restrict__ scales) {
  __shared__ float red[256];
  red[threadIdx.x] = part[blockIdx.x * 256 + threadIdx.x];
  __syncthreads();
  for (int st = 128; st > 0; st >>= 1) {
    if ((int)threadIdx.x < st) red[threadIdx.x] += red[threadIdx.x + st];
    __syncthreads();
  }
  if (threadIdx.x == 0) {
    float n = (blockIdx.x == 0) ? (float)(N_QKV * C_DIM) : (float)(C_DIM * C_DIM);
    scales[blockIdx.x] = fmaxf(red[0] / n, 1e-8f);
  }
}

// ---------------- ternarize -> bf16 (exact: {-1,0,1}) -----------------------
__global__ __launch_bounds__(256) void ternarize_k(const float* __restrict__ w,
                                                   ushort_t* __restrict__ wt, int n,
                                                   const float* __restrict__ scales,
                                                   int which) {
  int i = blockIdx.x * 256 + threadIdx.x;
  if (i < n) {
    float s = scales[which];
    float t = rintf(w[i] / s);           // round-half-even matches jnp.round
    wt[i] = f2bf(fminf(1.f, fmaxf(-1.f, t)));
  }
}

// ---------------- fp32 -> bf16 hi/lo split ----------------------------------
__global__ __launch_bounds__(256) void split_hl_k(const float* __restrict__ in,
                                                  ushort_t* __restrict__ hi,
                                                  ushort_t* __restrict__ lo, int n4) {
  int i = blockIdx.x * 256 + threadIdx.x;
  if (i < n4) {
    const float4 v = ((const float4*)in)[i];
    const float vv[4] = {v.x, v.y, v.z, v.w};
    ushort_t hh[4], ll[4];
#pragma unroll
    for (int j = 0; j < 4; ++j) {
      hh[j] = f2bf(vv[j]);
      ll[j] = f2bf(vv[j] - bf2f(hh[j]));
    }
    ((ushort4*)hi)[i] = make_ushort4(hh[0], hh[1], hh[2], hh[3]);
    ((ushort4*)lo)[i] = make_ushort4(ll[0], ll[1], ll[2], ll[3]);
  }
}

// ---------------- bf16 MFMA GEMM, A split hi/lo (Q/K columns) ---------------
__global__ __launch_bounds__(256) void gemm_bf16_hl(const ushort_t* __restrict__ Ah,
                                                    const ushort_t* __restrict__ Al,
                                                    const ushort_t* __restrict__ Bw,
                                                    float* __restrict__ C,
                                                    int Nd, int Kd) {
  __shared__ __align__(16) char lds[49152];   // Ah 16K | Al 16K | B 16K
  const int tid = threadIdx.x;
  const int bm = blockIdx.y << 7, bn = blockIdx.x << 7;
  const int w = tid >> 6, lane = tid & 63;
  const int wm = (w >> 1) << 6, wn = (w & 1) << 6;
  const int fr = lane & 15, fc = lane >> 4;

  int srow[4], scol[4];
#pragma unroll
  for (int i = 0; i < 4; ++i) {
    const int slot = i * 256 + tid;
    const int r = slot >> 3, s = slot & 7;
    srow[i] = r;
    scol[i] = (s ^ (r & 7)) << 3;            // pre-swizzled source column
  }

  f32x4 acc[4][4];
  const f32x4 z = {0.f, 0.f, 0.f, 0.f};
#pragma unroll
  for (int i = 0; i < 4; ++i)
#pragma unroll
    for (int j = 0; j < 4; ++j) acc[i][j] = z;

  for (int k0 = 0; k0 < Kd; k0 += 64) {
    __syncthreads();
#pragma unroll
    for (int i = 0; i < 4; ++i) {
      const int d16 = (i * 256 + tid) * 16;
      const size_t ga = (size_t)(bm + srow[i]) * Kd + k0 + scol[i];
      const size_t gb = (size_t)(bn + srow[i]) * Kd + k0 + scol[i];
      gll16((const char*)(Ah + ga), lds + d16);
      gll16((const char*)(Al + ga), lds + 16384 + d16);
      gll16((const char*)(Bw + gb), lds + 32768 + d16);
    }
    __syncthreads();
#pragma unroll
    for (int ks = 0; ks < 2; ++ks) {
      short8 af[4], lf[4], bf[4];
#pragma unroll
      for (int i = 0; i < 4; ++i) {
        const int ra = wm + i * 16 + fr;
        const int ca = (ks * 64 + fc * 16) ^ ((ra & 7) << 4);
        af[i] = *(const short8*)(lds + ra * 128 + ca);
        lf[i] = *(const short8*)(lds + 16384 + ra * 128 + ca);
        const int rb = wn + i * 16 + fr;
        const int cbb = (ks * 64 + fc * 16) ^ ((rb & 7) << 4);
        bf[i] = *(const short8*)(lds + 32768 + rb * 128 + cbb);
      }
#pragma unroll
      for (int i = 0; i < 4; ++i)
#pragma unroll
        for (int j = 0; j < 4; ++j) {
          acc[i][j] = __builtin_amdgcn_mfma_f32_16x16x32_bf16(af[i], bf[j], acc[i][j], 0, 0, 0);
          acc[i][j] = __builtin_amdgcn_mfma_f32_16x16x32_bf16(lf[i], bf[j], acc[i][j], 0, 0, 0);
        }
    }
  }
#pragma unroll
  for (int i = 0; i < 4; ++i)
#pragma unroll
    for (int j = 0; j < 4; ++j) {
      float* cp = C + (size_t)(bm + wm + i * 16 + fc * 4) * Nd + bn + wn + j * 16 + fr;
#pragma unroll
      for (int r = 0; r < 4; ++r) cp[(size_t)r * Nd] = acc[i][j][r];
    }
}

// ---------------- bf16 MFMA GEMM, single-pass A ----------------------------
// Used for V columns of gemm1 (C/Bw pointer-offset) and the out projection.
__global__ __launch_bounds__(256) void gemm_bf16(const ushort_t* __restrict__ A,
                                                 const ushort_t* __restrict__ Bw,
                                                 float* __restrict__ C,
                                                 int Nd, int Kd) {
  __shared__ __align__(16) char lds[32768];   // A 16K | B 16K
  const int tid = threadIdx.x;
  const int bm = blockIdx.y << 7, bn = blockIdx.x << 7;
  const int w = tid >> 6, lane = tid & 63;
  const int wm = (w >> 1) << 6, wn = (w & 1) << 6;
  const int fr = lane & 15, fc = lane >> 4;

  int srow[4], scol[4];
#pragma unroll
  for (int i = 0; i < 4; ++i) {
    const int slot = i * 256 + tid;
    const int r = slot >> 3, s = slot & 7;
    srow[i] = r;
    scol[i] = (s ^ (r & 7)) << 3;
  }

  f32x4 acc[4][4];
  const f32x4 z = {0.f, 0.f, 0.f, 0.f};
#pragma unroll
  for (int i = 0; i < 4; ++i)
#pragma unroll
    for (int j = 0; j < 4; ++j) acc[i][j] = z;

  for (int k0 = 0; k0 < Kd; k0 += 64) {
    __syncthreads();
#pragma unroll
    for (int i = 0; i < 4; ++i) {
      const int d16 = (i * 256 + tid) * 16;
      gll16((const char*)(A + (size_t)(bm + srow[i]) * Kd + k0 + scol[i]), lds + d16);
      gll16((const char*)(Bw + (size_t)(bn + srow[i]) * Kd + k0 + scol[i]), lds + 16384 + d16);
    }
    __syncthreads();
#pragma unroll
    for (int ks = 0; ks < 2; ++ks) {
      short8 af[4], bf[4];
#pragma unroll
      for (int i = 0; i < 4; ++i) {
        const int ra = wm + i * 16 + fr;
        af[i] = *(const short8*)(lds + ra * 128 + ((ks * 64 + fc * 16) ^ ((ra & 7) << 4)));
        const int rb = wn + i * 16 + fr;
        bf[i] = *(const short8*)(lds + 16384 + rb * 128 + ((ks * 64 + fc * 16) ^ ((rb & 7) << 4)));
      }
#pragma unroll
      for (int i = 0; i < 4; ++i)
#pragma unroll
        for (int j = 0; j < 4; ++j)
          acc[i][j] = __builtin_amdgcn_mfma_f32_16x16x32_bf16(af[i], bf[j], acc[i][j], 0, 0, 0);
    }
  }
#pragma unroll
  for (int i = 0; i < 4; ++i)
#pragma unroll
    for (int j = 0; j < 4; ++j) {
      float* cp = C + (size_t)(bm + wm + i * 16 + fc * 4) * Nd + bn + wn + j * 16 + fr;
#pragma unroll
      for (int r = 0; r < 4; ++r) cp[(size_t)r * Nd] = acc[i][j][r];
    }
}

// ---------------- prep_kv: per-(b,h,chunk) swizzled LDS images --------------
__global__ __launch_bounds__(256) void prep_kv_k(const float* __restrict__ qkv,
                                                 char* __restrict__ img) {
  __shared__ __align__(16) char sm[24576];
  const int tid = threadIdx.x;
  const int c = blockIdx.x & 31, gg = blockIdx.x >> 5;
  const int h = gg & 15, b = gg >> 4;
  const int key = tid >> 2, dg = tid & 3;
  const float* kp = qkv + (size_t)b * T_SEQ * N_QKV +
                    (size_t)(c * 64 + key) * N_QKV + C_DIM + (h << 6) + dg * 16;
  const float4 k0 = *(const float4*)(kp + 0);
  const float4 k1 = *(const float4*)(kp + 4);
  const float4 k2 = *(const float4*)(kp + 8);
  const float4 k3 = *(const float4*)(kp + 12);
  const float4 v0 = *(const float4*)(kp + C_DIM + 0);
  const float4 v1 = *(const float4*)(kp + C_DIM + 4);
  const float4 v2 = *(const float4*)(kp + C_DIM + 8);
  const float4 v3 = *(const float4*)(kp + C_DIM + 12);
  const float kv[16] = {k0.x,k0.y,k0.z,k0.w, k1.x,k1.y,k1.z,k1.w,
                        k2.x,k2.y,k2.z,k2.w, k3.x,k3.y,k3.z,k3.w};
  const float vv[16] = {v0.x,v0.y,v0.z,v0.w, v1.x,v1.y,v1.z,v1.w,
                        v2.x,v2.y,v2.z,v2.w, v3.x,v3.y,v3.z,v3.w};
  short8 khi0, khi1, klo0, klo1;
#pragma unroll
  for (int j = 0; j < 8; ++j) {
    const float x0 = kv[j], x1 = kv[8 + j];
    const unsigned short h0 = f2bf(x0), h1 = f2bf(x1);
    khi0[j] = (short)h0; khi1[j] = (short)h1;
    klo0[j] = (short)f2bf(x0 - bf2f(h0));
    klo1[j] = (short)f2bf(x1 - bf2f(h1));
  }
  const int sw = (key & 7) << 4;
  const int b0 = key * 128 + ((dg * 32) ^ sw);
  const int b1 = key * 128 + ((dg * 32 + 16) ^ sw);
  *(short8*)(sm + b0) = khi0;        *(short8*)(sm + b1) = khi1;
  *(short8*)(sm + 8192 + b0) = klo0; *(short8*)(sm + 8192 + b1) = klo1;
#pragma unroll
  for (int i = 0; i < 16; ++i) {
    const int d = dg * 16 + i;
    *(short*)(sm + 16384 + d * 128 + ((key * 2) ^ ((d & 7) << 4))) = (short)f2bf(vv[i]);
  }
  __syncthreads();
  int4* dst = (int4*)(img + (size_t)blockIdx.x * 24576);
  const int4* src = (const int4*)sm;
#pragma unroll
  for (int i = 0; i < 6; ++i) dst[i * 256 + tid] = src[i * 256 + tid];
}

// ---------------- swapped-QK single-tile MFMA flash attention ---------------
// R13 core (in-register P, exp2 domain, defer-max) but ONE q-tile per block:
// no P buffer -> dbuf is only 48KB -> 3 blocks/CU. Grid 1024 with
// DESCENDING-qt launch order (LPT schedule balances the causal skew across
// the 3 resident blocks/CU); gg in low 5 bits pins each img slice to an XCD.
struct TS2 { f32x4 O[4]; float m; float l; };

__device__ __forceinline__ void post_qk(f32x4* s4, TS2& st, const char* vTp,
                                        const bool diag, const int w, const int lg,
                                        const int lr, const int sh0, const int sh1) {
  if (diag) {
#pragma unroll
    for (int f = 0; f < 4; ++f)
#pragma unroll
      for (int r = 0; r < 4; ++r)
        if (16 * f + 4 * lg + r > w * 16 + lr) s4[f][r] = -1e30f;
  }
  float mc = fmaxf(fmaxf(s4[0][0], s4[0][1]), fmaxf(s4[0][2], s4[0][3]));
#pragma unroll
  for (int f = 1; f < 4; ++f)
#pragma unroll
    for (int r = 0; r < 4; ++r) mc = fmaxf(mc, s4[f][r]);
  if (__any(mc > st.m + 11.5f)) {          // defer-max (log2 units)
    mc = fmaxf(mc, __shfl_xor(mc, 16));
    mc = fmaxf(mc, __shfl_xor(mc, 32));
    const float mn = fmaxf(st.m, mc);
    const float rs = exp2f(st.m - mn);
    st.m = mn;
    st.l *= rs;
#pragma unroll
    for (int n = 0; n < 4; ++n)
#pragma unroll
      for (int r = 0; r < 4; ++r) st.O[n][r] *= rs;
  }
#pragma unroll
  for (int f = 0; f < 4; ++f)
#pragma unroll
    for (int r = 0; r < 4; ++r) s4[f][r] = exp2f(s4[f][r] - st.m);
#pragma unroll
  for (int f = 0; f < 4; ++f)
    st.l += (s4[f][0] + s4[f][1]) + (s4[f][2] + s4[f][3]);

  // pack adjacent key-pairs: D[f][rp] = bf16(p[2rp]) | bf16(p[2rp+1])<<16
  unsigned D[4][2];
#pragma unroll
  for (int f = 0; f < 4; ++f)
#pragma unroll
    for (int rp = 0; rp < 2; ++rp)
      D[f][rp] = (fbits(s4[f][2 * rp + 1]) & 0xFFFF0000u) | (fbits(s4[f][2 * rp]) >> 16);

  // gather group's P into B-operand order: slot(s,t) = D[2s+(lg>>1)][t&1]
  // from lane lr+32(lg&1)+16(t>>1)
  int g[4][2][2];
#pragma unroll
  for (int f = 0; f < 4; ++f)
#pragma unroll
    for (int rp = 0; rp < 2; ++rp) {
      g[f][rp][0] = __shfl((int)D[f][rp], sh0, 64);
      g[f][rp][1] = __shfl((int)D[f][rp], sh1, 64);
    }
  const bool hi2 = (lg & 2) != 0;
  union PB { int4 i; short8 s; } pb0, pb1;
  pb0.i.x = hi2 ? g[1][0][0] : g[0][0][0];
  pb0.i.y = hi2 ? g[1][1][0] : g[0][1][0];
  pb0.i.z = hi2 ? g[1][0][1] : g[0][0][1];
  pb0.i.w = hi2 ? g[1][1][1] : g[0][1][1];
  pb1.i.x = hi2 ? g[3][0][0] : g[2][0][0];
  pb1.i.y = hi2 ? g[3][1][0] : g[2][1][0];
  pb1.i.z = hi2 ? g[3][0][1] : g[2][0][1];
  pb1.i.w = hi2 ? g[3][1][1] : g[2][1][1];

  // PV: O^T[d][q] = mfma(A=V^T rows 16n+lr, B=P^T); V^T reads unchanged
  const int swz = (lr & 7) << 4;
#pragma unroll
  for (int n = 0; n < 4; ++n) {
    const int d = 16 * n + lr;
    const short8 va0 = *(const short8*)(vTp + d * 128 + ((lg * 16) ^ swz));
    st.O[n] = __builtin_amdgcn_mfma_f32_16x16x32_bf16(va0, pb0.s, st.O[n], 0, 0, 0);
    const short8 va1 = *(const short8*)(vTp + d * 128 + ((64 + lg * 16) ^ swz));
    st.O[n] = __builtin_amdgcn_mfma_f32_16x16x32_bf16(va1, pb1.s, st.O[n], 0, 0, 0);
  }
}

__device__ __forceinline__ void load_q(const float* base, int qt, int h,
                                       int w, int lg, int lr,
                                       short8* qh, short8* ql) {
  const float* qrow = base + (size_t)(qt * 64 + w * 16 + lr) * N_QKV + (h << 6);
#pragma unroll
  for (int s = 0; s < 2; ++s) {
    const float4 a0 = *(const float4*)(qrow + s * 32 + lg * 8);
    const float4 a1 = *(const float4*)(qrow + s * 32 + lg * 8 + 4);
    const float xv[8] = {a0.x, a0.y, a0.z, a0.w, a1.x, a1.y, a1.z, a1.w};
#pragma unroll
    for (int j = 0; j < 8; ++j) {
      const float xs = xv[j] * 0.1803368801f;   // (1/8) * log2(e): exp2 domain
      const unsigned short hs = f2bf(xs);
      qh[s][j] = (short)hs;
      ql[s][j] = (short)f2bf(xs - bf2f(hs));
    }
  }
}

__device__ __forceinline__ void store_o3(ushort_t* oh, TS2& st,
                                         int b, int qt, int h,
                                         int w, int lg, int lr) {
  float l = st.l;                          // lane-local partial (16 keys)
  l += __shfl_xor(l, 16);                  // sum over the 4-lane group
  l += __shfl_xor(l, 32);
  const float inv = 1.f / l;
  ushort_t* orow = oh + (size_t)(b * T_SEQ + qt * 64 + w * 16 + lr) * C_DIM
                   + (h << 6) + (lg << 2);
#pragma unroll
  for (int n = 0; n < 4; ++n) {
    ushort4 o;
    o.x = f2bf(st.O[n][0] * inv);
    o.y = f2bf(st.O[n][1] * inv);
    o.z = f2bf(st.O[n][2] * inv);
    o.w = f2bf(st.O[n][3] * inv);
    *(ushort4*)(orow + 16 * n) = o;        // d = 16n + 4lg + r
  }
}

__global__ __launch_bounds__(256) void attn1_k(const float* __restrict__ qkv,
                                               const char* __restrict__ img,
                                               ushort_t* __restrict__ oh) {
  __shared__ __align__(16) char smem[49152];   // buf0 24K | buf1 24K
  const int tid  = threadIdx.x;
  const int lane = tid & 63;
  const int w    = tid >> 6;
  const int lg   = lane >> 4;
  const int lr   = lane & 15;
  const int sh0  = lr + 32 * (lg & 1);     // P-gather source lanes
  const int sh1  = sh0 + 16;

  // gg in low 5 bits (XCD-pinned img slice); qt descending (LPT balance)
  const int bx = blockIdx.x;
  const int gg = bx & 31;
  const int qt = 31 - (bx >> 5);
  const int h  = gg & 15, b = gg >> 4;

  const float* base = qkv + (size_t)b * T_SEQ * N_QKV;
  const char* img_gg = img + (size_t)gg * 32 * 24576;

  short8 qh[2], ql[2];
  load_q(base, qt, h, w, lg, lr, qh, ql);

  TS2 st;
#pragma unroll
  for (int n = 0; n < 4; ++n) {
    const f32x4 z = {0.f, 0.f, 0.f, 0.f};
    st.O[n] = z;
  }
  st.m = -1e30f;
  st.l = 0.f;

  // prologue: issue chunk 0 into buf0
#pragma unroll
  for (int i = 0; i < 6; ++i)
    gll16(img_gg + i * 4096 + tid * 16, smem + i * 4096 + tid * 16);

  int cur = 0;
  for (int c = 0; c <= qt; ++c) {
    __syncthreads();                         // drains outstanding loads
    if (c < qt) {
      const char* src = img_gg + (size_t)(c + 1) * 24576;
      char* dst = smem + (cur ^ 1) * 24576;
#pragma unroll
      for (int i = 0; i < 6; ++i)
        gll16(src + i * 4096 + tid * 16, dst + i * 4096 + tid * 16);
    }
    const char* khp = smem + cur * 24576;
    const char* klp = khp + 8192;
    const char* vTp = khp + 16384;

    // ---- swapped QK: S^T = mfma(K, Q) ----
    f32x4 s4[4];
    const f32x4 z = {0.f, 0.f, 0.f, 0.f};
#pragma unroll
    for (int f = 0; f < 4; ++f) s4[f] = z;
#pragma unroll
    for (int s = 0; s < 2; ++s) {
      const int cb = s * 64 + lg * 16;
#pragma unroll
      for (int f = 0; f < 4; ++f) {
        const int row = lr + 16 * f;
        const int byt = row * 128 + (cb ^ ((row & 7) << 4));
        const short8 kh8 = *(const short8*)(khp + byt);
        const short8 kl8 = *(const short8*)(klp + byt);
        s4[f] = __builtin_amdgcn_mfma_f32_16x16x32_bf16(kh8, qh[s], s4[f], 0, 0, 0);
        s4[f] = __builtin_amdgcn_mfma_f32_16x16x32_bf16(kh8, ql[s], s4[f], 0, 0, 0);
        s4[f] = __builtin_amdgcn_mfma_f32_16x16x32_bf16(kl8, qh[s], s4[f], 0, 0, 0);
      }
    }
    post_qk(s4, st, vTp, c == qt, w, lg, lr, sh0, sh1);

    cur ^= 1;
  }

  store_o3(oh, st, b, qt, h, w, lg, lr);
}

// ---------------- launch ----------------------------------------------------
extern "C" void kernel_launch(void* const* d_in, const int* in_sizes, int n_in,
                              void* d_out, int out_size, void* d_ws, size_t ws_size,
                              hipStream_t stream) {
  const float* x      = (const float*)d_in[0];   // [4096][1024]
  const float* w_qkv  = (const float*)d_in[1];   // [3072][1024]
  const float* w_out  = (const float*)d_in[2];   // [1024][1024]
  float* out = (float*)d_out;                    // [4096][1024]

  // layout (img aliases wt_qkv, which is dead after gemm1; stream-ordered)
  char* pch = (char*)d_ws;
  ushort_t* wt_out = (ushort_t*)pch;  pch += (size_t)C_DIM * C_DIM * 2;    // 2MB
  ushort_t* xh     = (ushort_t*)pch;  pch += (size_t)M_ROWS * C_DIM * 2;   // 8MB
  ushort_t* xl     = (ushort_t*)pch;  pch += (size_t)M_ROWS * C_DIM * 2;   // 8MB
  float*    qkv    = (float*)pch;     pch += (size_t)M_ROWS * N_QKV * 4;   // 48MB
  ushort_t* wt_qkv = (ushort_t*)pch;                                       // 6MB..
  char*     img    = pch;             pch += (size_t)1024 * 24576;         // 25.2MB
  float*    part   = (float*)pch;     pch += 512 * 4;
  float*    scales = (float*)pch;
  ushort_t* ah = xh;   // x hi dead after gemm1 -> attn output

  hipLaunchKernelGGL(abs_partial_k, dim3(256), dim3(256), 0, stream,
                     w_qkv, N_QKV * C_DIM, part);
  hipLaunchKernelGGL(abs_partial_k, dim3(256), dim3(256), 0, stream,
                     w_out, C_DIM * C_DIM, part + 256);
  hipLaunchKernelGGL(finalize_scales_k, dim3(2), dim3(256), 0, stream, part, scales);

  hipLaunchKernelGGL(ternarize_k, dim3((N_QKV * C_DIM) / 256), dim3(256), 0, stream,
                     w_qkv, wt_qkv, N_QKV * C_DIM, scales, 0);
  hipLaunchKernelGGL(ternarize_k, dim3((C_DIM * C_DIM) / 256), dim3(256), 0, stream,
                     w_out, wt_out, C_DIM * C_DIM, scales, 1);

  hipLaunchKernelGGL(split_hl_k, dim3((M_ROWS * C_DIM / 4) / 256), dim3(256), 0, stream,
                     x, xh, xl, M_ROWS * C_DIM / 4);

  // gemm1a: q,k columns (N=0..2048) with hi/lo precision
  hipLaunchKernelGGL(gemm_bf16_hl, dim3(2048 / 128, M_ROWS / 128), dim3(256), 0, stream,
                     xh, xl, wt_qkv, qkv, N_QKV, C_DIM);
  // gemm1b: v columns (N=2048..3072) plain bf16 (V re-rounds to bf16 anyway)
  hipLaunchKernelGGL(gemm_bf16, dim3(1024 / 128, M_ROWS / 128), dim3(256), 0, stream,
                     xh, wt_qkv + (size_t)2048 * C_DIM, qkv + 2048, N_QKV, C_DIM);

  // K/V chunk images (overwrites wt_qkv region — dead now)
  hipLaunchKernelGGL(prep_kv_k, dim3(1024), dim3(256), 0, stream, qkv, img);

  // attention -> bf16 (single-tile blocks, LPT order)
  hipLaunchKernelGGL(attn1_k, dim3(1024), dim3(256), 0, stream, qkv, img, ah);

  // out = ah @ wt_out^T
  hipLaunchKernelGGL(gemm_bf16, dim3(C_DIM / 128, M_ROWS / 128), dim3(256), 0, stream,
                     ah, wt_out, out, C_DIM, C_DIM);
}

// Round 15
// 173.083 us; speedup vs baseline: 1.2333x; 1.0912x over previous
//
#include <hip/hip_runtime.h>
#include <math.h>

#define T_SEQ 2048
#define C_DIM 1024
#define NHEAD 16
#define HDIM 64
#define M_ROWS 4096   // B*T
#define N_QKV 3072    // 3*C

typedef __attribute__((ext_vector_type(8))) short short8;   // 8 bf16 (4 VGPR)
typedef __attribute__((ext_vector_type(4))) float f32x4;    // MFMA C/D
typedef unsigned short ushort_t;

__device__ inline unsigned short f2bf(float x) {            // RNE f32->bf16
  union { float f; unsigned u; } v; v.f = x;
  unsigned r = v.u + 0x7FFF + ((v.u >> 16) & 1);
  return (unsigned short)(r >> 16);
}
__device__ inline float bf2f(unsigned short h) {
  union { unsigned u; float f; } v; v.u = ((unsigned)h) << 16; return v.f;
}
__device__ inline unsigned fbits(float x) {
  union { float f; unsigned u; } v; v.f = x; return v.u;
}

// async global->LDS, 16B per lane; LDS dest = wave-uniform base + lane*16
__device__ __forceinline__ void gll16(const char* g, char* l) {
  __builtin_amdgcn_global_load_lds(
      (const __attribute__((address_space(1))) unsigned*)g,
      (__attribute__((address_space(3))) unsigned*)l, 16, 0, 0);
}

// ---------------- fused abs-sum pass (both weights, one launch) -------------
// blocks 0..255 -> w_qkv (3.1M elems); blocks 256..383 -> w_out (1.05M)
__global__ __launch_bounds__(256) void abs2_k(const float* __restrict__ w_qkv,
                                              const float* __restrict__ w_out,
                                              float* __restrict__ part) {
  __shared__ float red[256];
  const int bx = blockIdx.x;
  const float* w;
  int n, nblk, bi;
  if (bx < 256) { w = w_qkv; n = N_QKV * C_DIM; nblk = 256; bi = bx; }
  else          { w = w_out; n = C_DIM * C_DIM; nblk = 128; bi = bx - 256; }
  float s = 0.f;
  for (int i = bi * 256 + threadIdx.x; i < n; i += nblk * 256)
    s += fabsf(w[i]);
  red[threadIdx.x] = s;
  __syncthreads();
  for (int st = 128; st > 0; st >>= 1) {
    if ((int)threadIdx.x < st) red[threadIdx.x] += red[threadIdx.x + st];
    __syncthreads();
  }
  if (threadIdx.x == 0) part[bx] = red[0];
}

__global__ __launch_bounds__(256) void finalize2_k(const float* __restrict__ part,
                                                   float* __restrict__ scales) {
  __shared__ float red[256];
  const int bx = blockIdx.x;
  const int lim = (bx == 0) ? 256 : 128;
  red[threadIdx.x] = ((int)threadIdx.x < lim) ? part[bx * 256 + threadIdx.x] : 0.f;
  __syncthreads();
  for (int st = 128; st > 0; st >>= 1) {
    if ((int)threadIdx.x < st) red[threadIdx.x] += red[threadIdx.x + st];
    __syncthreads();
  }
  if (threadIdx.x == 0) {
    float n = (bx == 0) ? (float)(N_QKV * C_DIM) : (float)(C_DIM * C_DIM);
    scales[bx] = fmaxf(red[0] / n, 1e-8f);
  }
}

// ---------------- fused elementwise: ternarize both weights + split x -------
// bx ranges: [0,12288) tern qkv; [12288,16384) tern out; [16384,20480) split x.
__global__ __launch_bounds__(256) void prep_elem_k(const float* __restrict__ w_qkv,
                                                   const float* __restrict__ w_out,
                                                   const float* __restrict__ x,
                                                   ushort_t* __restrict__ wt_qkv,
                                                   ushort_t* __restrict__ wt_out,
                                                   ushort_t* __restrict__ xh,
                                                   ushort_t* __restrict__ xl,
                                                   const float* __restrict__ scales) {
  const int bx = blockIdx.x;
  if (bx < 12288) {
    const int i = bx * 256 + threadIdx.x;
    const float s = scales[0];
    const float t = rintf(w_qkv[i] / s);
    wt_qkv[i] = f2bf(fminf(1.f, fmaxf(-1.f, t)));
  } else if (bx < 16384) {
    const int i = (bx - 12288) * 256 + threadIdx.x;
    const float s = scales[1];
    const float t = rintf(w_out[i] / s);
    wt_out[i] = f2bf(fminf(1.f, fmaxf(-1.f, t)));
  } else {
    const int i = (bx - 16384) * 256 + threadIdx.x;     // float4 index
    const float4 v = ((const float4*)x)[i];
    const float vv[4] = {v.x, v.y, v.z, v.w};
    ushort_t hh[4], ll[4];
#pragma unroll
    for (int j = 0; j < 4; ++j) {
      hh[j] = f2bf(vv[j]);
      ll[j] = f2bf(vv[j] - bf2f(hh[j]));
    }
    ((ushort4*)xh)[i] = make_ushort4(hh[0], hh[1], hh[2], hh[3]);
    ((ushort4*)xl)[i] = make_ushort4(ll[0], ll[1], ll[2], ll[3]);
  }
}

// ---------------- bf16 MFMA GEMM, A split hi/lo (qkv projection) ------------
__global__ __launch_bounds__(256) void gemm_bf16_hl(const ushort_t* __restrict__ Ah,
                                                    const ushort_t* __restrict__ Al,
                                                    const ushort_t* __restrict__ Bw,
                                                    float* __restrict__ C,
                                                    int Nd, int Kd) {
  __shared__ __align__(16) char lds[49152];   // Ah 16K | Al 16K | B 16K
  const int tid = threadIdx.x;
  const int bm = blockIdx.y << 7, bn = blockIdx.x << 7;
  const int w = tid >> 6, lane = tid & 63;
  const int wm = (w >> 1) << 6, wn = (w & 1) << 6;
  const int fr = lane & 15, fc = lane >> 4;

  int srow[4], scol[4];
#pragma unroll
  for (int i = 0; i < 4; ++i) {
    const int slot = i * 256 + tid;
    const int r = slot >> 3, s = slot & 7;
    srow[i] = r;
    scol[i] = (s ^ (r & 7)) << 3;            // pre-swizzled source column
  }

  f32x4 acc[4][4];
  const f32x4 z = {0.f, 0.f, 0.f, 0.f};
#pragma unroll
  for (int i = 0; i < 4; ++i)
#pragma unroll
    for (int j = 0; j < 4; ++j) acc[i][j] = z;

  for (int k0 = 0; k0 < Kd; k0 += 64) {
    __syncthreads();
#pragma unroll
    for (int i = 0; i < 4; ++i) {
      const int d16 = (i * 256 + tid) * 16;
      const size_t ga = (size_t)(bm + srow[i]) * Kd + k0 + scol[i];
      const size_t gb = (size_t)(bn + srow[i]) * Kd + k0 + scol[i];
      gll16((const char*)(Ah + ga), lds + d16);
      gll16((const char*)(Al + ga), lds + 16384 + d16);
      gll16((const char*)(Bw + gb), lds + 32768 + d16);
    }
    __syncthreads();
#pragma unroll
    for (int ks = 0; ks < 2; ++ks) {
      short8 af[4], lf[4], bf[4];
#pragma unroll
      for (int i = 0; i < 4; ++i) {
        const int ra = wm + i * 16 + fr;
        const int ca = (ks * 64 + fc * 16) ^ ((ra & 7) << 4);
        af[i] = *(const short8*)(lds + ra * 128 + ca);
        lf[i] = *(const short8*)(lds + 16384 + ra * 128 + ca);
        const int rb = wn + i * 16 + fr;
        const int cbb = (ks * 64 + fc * 16) ^ ((rb & 7) << 4);
        bf[i] = *(const short8*)(lds + 32768 + rb * 128 + cbb);
      }
#pragma unroll
      for (int i = 0; i < 4; ++i)
#pragma unroll
        for (int j = 0; j < 4; ++j) {
          acc[i][j] = __builtin_amdgcn_mfma_f32_16x16x32_bf16(af[i], bf[j], acc[i][j], 0, 0, 0);
          acc[i][j] = __builtin_amdgcn_mfma_f32_16x16x32_bf16(lf[i], bf[j], acc[i][j], 0, 0, 0);
        }
    }
  }
#pragma unroll
  for (int i = 0; i < 4; ++i)
#pragma unroll
    for (int j = 0; j < 4; ++j) {
      float* cp = C + (size_t)(bm + wm + i * 16 + fc * 4) * Nd + bn + wn + j * 16 + fr;
#pragma unroll
      for (int r = 0; r < 4; ++r) cp[(size_t)r * Nd] = acc[i][j][r];
    }
}

// ---------------- bf16 MFMA GEMM, single-pass A (out projection) ------------
__global__ __launch_bounds__(256) void gemm_bf16(const ushort_t* __restrict__ A,
                                                 const ushort_t* __restrict__ Bw,
                                                 float* __restrict__ C,
                                                 int Nd, int Kd) {
  __shared__ __align__(16) char lds[32768];   // A 16K | B 16K
  const int tid = threadIdx.x;
  const int bm = blockIdx.y << 7, bn = blockIdx.x << 7;
  const int w = tid >> 6, lane = tid & 63;
  const int wm = (w >> 1) << 6, wn = (w & 1) << 6;
  const int fr = lane & 15, fc = lane >> 4;

  int srow[4], scol[4];
#pragma unroll
  for (int i = 0; i < 4; ++i) {
    const int slot = i * 256 + tid;
    const int r = slot >> 3, s = slot & 7;
    srow[i] = r;
    scol[i] = (s ^ (r & 7)) << 3;
  }

  f32x4 acc[4][4];
  const f32x4 z = {0.f, 0.f, 0.f, 0.f};
#pragma unroll
  for (int i = 0; i < 4; ++i)
#pragma unroll
    for (int j = 0; j < 4; ++j) acc[i][j] = z;

  for (int k0 = 0; k0 < Kd; k0 += 64) {
    __syncthreads();
#pragma unroll
    for (int i = 0; i < 4; ++i) {
      const int d16 = (i * 256 + tid) * 16;
      gll16((const char*)(A + (size_t)(bm + srow[i]) * Kd + k0 + scol[i]), lds + d16);
      gll16((const char*)(Bw + (size_t)(bn + srow[i]) * Kd + k0 + scol[i]), lds + 16384 + d16);
    }
    __syncthreads();
#pragma unroll
    for (int ks = 0; ks < 2; ++ks) {
      short8 af[4], bf[4];
#pragma unroll
      for (int i = 0; i < 4; ++i) {
        const int ra = wm + i * 16 + fr;
        af[i] = *(const short8*)(lds + ra * 128 + ((ks * 64 + fc * 16) ^ ((ra & 7) << 4)));
        const int rb = wn + i * 16 + fr;
        bf[i] = *(const short8*)(lds + 16384 + rb * 128 + ((ks * 64 + fc * 16) ^ ((rb & 7) << 4)));
      }
#pragma unroll
      for (int i = 0; i < 4; ++i)
#pragma unroll
        for (int j = 0; j < 4; ++j)
          acc[i][j] = __builtin_amdgcn_mfma_f32_16x16x32_bf16(af[i], bf[j], acc[i][j], 0, 0, 0);
    }
  }
#pragma unroll
  for (int i = 0; i < 4; ++i)
#pragma unroll
    for (int j = 0; j < 4; ++j) {
      float* cp = C + (size_t)(bm + wm + i * 16 + fc * 4) * Nd + bn + wn + j * 16 + fr;
#pragma unroll
      for (int r = 0; r < 4; ++r) cp[(size_t)r * Nd] = acc[i][j][r];
    }
}

// ---------------- prep_kv: per-(b,h,chunk) swizzled LDS images --------------
__global__ __launch_bounds__(256) void prep_kv_k(const float* __restrict__ qkv,
                                                 char* __restrict__ img) {
  __shared__ __align__(16) char sm[24576];
  const int tid = threadIdx.x;
  const int c = blockIdx.x & 31, gg = blockIdx.x >> 5;
  const int h = gg & 15, b = gg >> 4;
  const int key = tid >> 2, dg = tid & 3;
  const float* kp = qkv + (size_t)b * T_SEQ * N_QKV +
                    (size_t)(c * 64 + key) * N_QKV + C_DIM + (h << 6) + dg * 16;
  const float4 k0 = *(const float4*)(kp + 0);
  const float4 k1 = *(const float4*)(kp + 4);
  const float4 k2 = *(const float4*)(kp + 8);
  const float4 k3 = *(const float4*)(kp + 12);
  const float4 v0 = *(const float4*)(kp + C_DIM + 0);
  const float4 v1 = *(const float4*)(kp + C_DIM + 4);
  const float4 v2 = *(const float4*)(kp + C_DIM + 8);
  const float4 v3 = *(const float4*)(kp + C_DIM + 12);
  const float kv[16] = {k0.x,k0.y,k0.z,k0.w, k1.x,k1.y,k1.z,k1.w,
                        k2.x,k2.y,k2.z,k2.w, k3.x,k3.y,k3.z,k3.w};
  const float vv[16] = {v0.x,v0.y,v0.z,v0.w, v1.x,v1.y,v1.z,v1.w,
                        v2.x,v2.y,v2.z,v2.w, v3.x,v3.y,v3.z,v3.w};
  short8 khi0, khi1, klo0, klo1;
#pragma unroll
  for (int j = 0; j < 8; ++j) {
    const float x0 = kv[j], x1 = kv[8 + j];
    const unsigned short h0 = f2bf(x0), h1 = f2bf(x1);
    khi0[j] = (short)h0; khi1[j] = (short)h1;
    klo0[j] = (short)f2bf(x0 - bf2f(h0));
    klo1[j] = (short)f2bf(x1 - bf2f(h1));
  }
  const int sw = (key & 7) << 4;
  const int b0 = key * 128 + ((dg * 32) ^ sw);
  const int b1 = key * 128 + ((dg * 32 + 16) ^ sw);
  *(short8*)(sm + b0) = khi0;        *(short8*)(sm + b1) = khi1;
  *(short8*)(sm + 8192 + b0) = klo0; *(short8*)(sm + 8192 + b1) = klo1;
#pragma unroll
  for (int i = 0; i < 16; ++i) {
    const int d = dg * 16 + i;
    *(short*)(sm + 16384 + d * 128 + ((key * 2) ^ ((d & 7) << 4))) = (short)f2bf(vv[i]);
  }
  __syncthreads();
  int4* dst = (int4*)(img + (size_t)blockIdx.x * 24576);
  const int4* src = (const int4*)sm;
#pragma unroll
  for (int i = 0; i < 6; ++i) dst[i * 256 + tid] = src[i * 256 + tid];
}

// ---------------- swapped-QK single-tile attention, single-buffered ---------
// 24KB LDS (one chunk image, no dbuf) -> 4 blocks/CU at grid 1024; inter-block
// TLP hides the per-chunk load stall (R14 removed the blockers that sank R7:
// grid is 4 blocks/CU and VGPR 76). LPT launch order balances causal skew.
struct TS2 { f32x4 O[4]; float m; float l; };

__device__ __forceinline__ void post_qk(f32x4* s4, TS2& st, const char* vTp,
                                        const bool diag, const int w, const int lg,
                                        const int lr, const int sh0, const int sh1) {
  if (diag) {
#pragma unroll
    for (int f = 0; f < 4; ++f)
#pragma unroll
      for (int r = 0; r < 4; ++r)
        if (16 * f + 4 * lg + r > w * 16 + lr) s4[f][r] = -1e30f;
  }
  float mc = fmaxf(fmaxf(s4[0][0], s4[0][1]), fmaxf(s4[0][2], s4[0][3]));
#pragma unroll
  for (int f = 1; f < 4; ++f)
#pragma unroll
    for (int r = 0; r < 4; ++r) mc = fmaxf(mc, s4[f][r]);
  if (__any(mc > st.m + 11.5f)) {          // defer-max (log2 units)
    mc = fmaxf(mc, __shfl_xor(mc, 16));
    mc = fmaxf(mc, __shfl_xor(mc, 32));
    const float mn = fmaxf(st.m, mc);
    const float rs = exp2f(st.m - mn);
    st.m = mn;
    st.l *= rs;
#pragma unroll
    for (int n = 0; n < 4; ++n)
#pragma unroll
      for (int r = 0; r < 4; ++r) st.O[n][r] *= rs;
  }
#pragma unroll
  for (int f = 0; f < 4; ++f)
#pragma unroll
    for (int r = 0; r < 4; ++r) s4[f][r] = exp2f(s4[f][r] - st.m);
#pragma unroll
  for (int f = 0; f < 4; ++f)
    st.l += (s4[f][0] + s4[f][1]) + (s4[f][2] + s4[f][3]);

  // pack adjacent key-pairs: D[f][rp] = bf16(p[2rp]) | bf16(p[2rp+1])<<16
  unsigned D[4][2];
#pragma unroll
  for (int f = 0; f < 4; ++f)
#pragma unroll
    for (int rp = 0; rp < 2; ++rp)
      D[f][rp] = (fbits(s4[f][2 * rp + 1]) & 0xFFFF0000u) | (fbits(s4[f][2 * rp]) >> 16);

  // gather group's P into B-operand order: slot(s,t) = D[2s+(lg>>1)][t&1]
  // from lane lr+32(lg&1)+16(t>>1)
  int g[4][2][2];
#pragma unroll
  for (int f = 0; f < 4; ++f)
#pragma unroll
    for (int rp = 0; rp < 2; ++rp) {
      g[f][rp][0] = __shfl((int)D[f][rp], sh0, 64);
      g[f][rp][1] = __shfl((int)D[f][rp], sh1, 64);
    }
  const bool hi2 = (lg & 2) != 0;
  union PB { int4 i; short8 s; } pb0, pb1;
  pb0.i.x = hi2 ? g[1][0][0] : g[0][0][0];
  pb0.i.y = hi2 ? g[1][1][0] : g[0][1][0];
  pb0.i.z = hi2 ? g[1][0][1] : g[0][0][1];
  pb0.i.w = hi2 ? g[1][1][1] : g[0][1][1];
  pb1.i.x = hi2 ? g[3][0][0] : g[2][0][0];
  pb1.i.y = hi2 ? g[3][1][0] : g[2][1][0];
  pb1.i.z = hi2 ? g[3][0][1] : g[2][0][1];
  pb1.i.w = hi2 ? g[3][1][1] : g[2][1][1];

  // PV: O^T[d][q] = mfma(A=V^T rows 16n+lr, B=P^T)
  const int swz = (lr & 7) << 4;
#pragma unroll
  for (int n = 0; n < 4; ++n) {
    const int d = 16 * n + lr;
    const short8 va0 = *(const short8*)(vTp + d * 128 + ((lg * 16) ^ swz));
    st.O[n] = __builtin_amdgcn_mfma_f32_16x16x32_bf16(va0, pb0.s, st.O[n], 0, 0, 0);
    const short8 va1 = *(const short8*)(vTp + d * 128 + ((64 + lg * 16) ^ swz));
    st.O[n] = __builtin_amdgcn_mfma_f32_16x16x32_bf16(va1, pb1.s, st.O[n], 0, 0, 0);
  }
}

__device__ __forceinline__ void load_q(const float* base, int qt, int h,
                                       int w, int lg, int lr,
                                       short8* qh, short8* ql) {
  const float* qrow = base + (size_t)(qt * 64 + w * 16 + lr) * N_QKV + (h << 6);
#pragma unroll
  for (int s = 0; s < 2; ++s) {
    const float4 a0 = *(const float4*)(qrow + s * 32 + lg * 8);
    const float4 a1 = *(const float4*)(qrow + s * 32 + lg * 8 + 4);
    const float xv[8] = {a0.x, a0.y, a0.z, a0.w, a1.x, a1.y, a1.z, a1.w};
#pragma unroll
    for (int j = 0; j < 8; ++j) {
      const float xs = xv[j] * 0.1803368801f;   // (1/8) * log2(e): exp2 domain
      const unsigned short hs = f2bf(xs);
      qh[s][j] = (short)hs;
      ql[s][j] = (short)f2bf(xs - bf2f(hs));
    }
  }
}

__device__ __forceinline__ void store_o3(ushort_t* oh, TS2& st,
                                         int b, int qt, int h,
                                         int w, int lg, int lr) {
  float l = st.l;                          // lane-local partial (16 keys)
  l += __shfl_xor(l, 16);                  // sum over the 4-lane group
  l += __shfl_xor(l, 32);
  const float inv = 1.f / l;
  ushort_t* orow = oh + (size_t)(b * T_SEQ + qt * 64 + w * 16 + lr) * C_DIM
                   + (h << 6) + (lg << 2);
#pragma unroll
  for (int n = 0; n < 4; ++n) {
    ushort4 o;
    o.x = f2bf(st.O[n][0] * inv);
    o.y = f2bf(st.O[n][1] * inv);
    o.z = f2bf(st.O[n][2] * inv);
    o.w = f2bf(st.O[n][3] * inv);
    *(ushort4*)(orow + 16 * n) = o;        // d = 16n + 4lg + r
  }
}

__global__ __launch_bounds__(256) void attn1_k(const float* __restrict__ qkv,
                                               const char* __restrict__ img,
                                               ushort_t* __restrict__ oh) {
  __shared__ __align__(16) char smem[24576];   // single chunk image
  const int tid  = threadIdx.x;
  const int lane = tid & 63;
  const int w    = tid >> 6;
  const int lg   = lane >> 4;
  const int lr   = lane & 15;
  const int sh0  = lr + 32 * (lg & 1);     // P-gather source lanes
  const int sh1  = sh0 + 16;

  // gg in low 5 bits (XCD-pinned img slice); qt descending (LPT balance)
  const int bx = blockIdx.x;
  const int gg = bx & 31;
  const int qt = 31 - (bx >> 5);
  const int h  = gg & 15, b = gg >> 4;

  const float* base = qkv + (size_t)b * T_SEQ * N_QKV;
  const char* img_gg = img + (size_t)gg * 32 * 24576;

  short8 qh[2], ql[2];
  load_q(base, qt, h, w, lg, lr, qh, ql);

  TS2 st;
#pragma unroll
  for (int n = 0; n < 4; ++n) {
    const f32x4 z = {0.f, 0.f, 0.f, 0.f};
    st.O[n] = z;
  }
  st.m = -1e30f;
  st.l = 0.f;

  for (int c = 0; c <= qt; ++c) {
    __syncthreads();                         // prev compute done (noop at c=0)
    const char* src = img_gg + (size_t)c * 24576;
#pragma unroll
    for (int i = 0; i < 6; ++i)
      gll16(src + i * 4096 + tid * 16, smem + i * 4096 + tid * 16);
    __syncthreads();                         // vmcnt drained -> image ready

    const char* khp = smem;
    const char* klp = smem + 8192;
    const char* vTp = smem + 16384;

    // ---- swapped QK: S^T = mfma(K, Q) ----
    f32x4 s4[4];
    const f32x4 z = {0.f, 0.f, 0.f, 0.f};
#pragma unroll
    for (int f = 0; f < 4; ++f) s4[f] = z;
#pragma unroll
    for (int s = 0; s < 2; ++s) {
      const int cb = s * 64 + lg * 16;
#pragma unroll
      for (int f = 0; f < 4; ++f) {
        const int row = lr + 16 * f;
        const int byt = row * 128 + (cb ^ ((row & 7) << 4));
        const short8 kh8 = *(const short8*)(khp + byt);
        const short8 kl8 = *(const short8*)(klp + byt);
        s4[f] = __builtin_amdgcn_mfma_f32_16x16x32_bf16(kh8, qh[s], s4[f], 0, 0, 0);
        s4[f] = __builtin_amdgcn_mfma_f32_16x16x32_bf16(kh8, ql[s], s4[f], 0, 0, 0);
        s4[f] = __builtin_amdgcn_mfma_f32_16x16x32_bf16(kl8, qh[s], s4[f], 0, 0, 0);
      }
    }
    post_qk(s4, st, vTp, c == qt, w, lg, lr, sh0, sh1);
  }

  store_o3(oh, st, b, qt, h, w, lg, lr);
}

// ---------------- launch ----------------------------------------------------
extern "C" void kernel_launch(void* const* d_in, const int* in_sizes, int n_in,
                              void* d_out, int out_size, void* d_ws, size_t ws_size,
                              hipStream_t stream) {
  const float* x      = (const float*)d_in[0];   // [4096][1024]
  const float* w_qkv  = (const float*)d_in[1];   // [3072][1024]
  const float* w_out  = (const float*)d_in[2];   // [1024][1024]
  float* out = (float*)d_out;                    // [4096][1024]

  // layout (img aliases wt_qkv, which is dead after gemm1; stream-ordered)
  char* pch = (char*)d_ws;
  ushort_t* wt_out = (ushort_t*)pch;  pch += (size_t)C_DIM * C_DIM * 2;    // 2MB
  ushort_t* xh     = (ushort_t*)pch;  pch += (size_t)M_ROWS * C_DIM * 2;   // 8MB
  ushort_t* xl     = (ushort_t*)pch;  pch += (size_t)M_ROWS * C_DIM * 2;   // 8MB
  float*    qkv    = (float*)pch;     pch += (size_t)M_ROWS * N_QKV * 4;   // 48MB
  ushort_t* wt_qkv = (ushort_t*)pch;                                       // 6MB..
  char*     img    = pch;             pch += (size_t)1024 * 24576;         // 25.2MB
  float*    part   = (float*)pch;     pch += 512 * 4;
  float*    scales = (float*)pch;
  ushort_t* ah = xh;   // x hi dead after gemm1 -> attn output

  hipLaunchKernelGGL(abs2_k, dim3(384), dim3(256), 0, stream, w_qkv, w_out, part);
  hipLaunchKernelGGL(finalize2_k, dim3(2), dim3(256), 0, stream, part, scales);

  hipLaunchKernelGGL(prep_elem_k, dim3(20480), dim3(256), 0, stream,
                     w_qkv, w_out, x, wt_qkv, wt_out, xh, xl, scales);

  // qkv = (xh+xl) @ wt_qkv^T  (fused hi/lo over all 3072 columns)
  hipLaunchKernelGGL(gemm_bf16_hl, dim3(N_QKV / 128, M_ROWS / 128), dim3(256), 0, stream,
                     xh, xl, wt_qkv, qkv, N_QKV, C_DIM);

  // K/V chunk images (overwrites wt_qkv region — dead now)
  hipLaunchKernelGGL(prep_kv_k, dim3(1024), dim3(256), 0, stream, qkv, img);

  // attention -> bf16 (single-tile, single-buffer 24KB, LPT order)
  hipLaunchKernelGGL(attn1_k, dim3(1024), dim3(256), 0, stream, qkv, img, ah);

  // out = ah @ wt_out^T
  hipLaunchKernelGGL(gemm_bf16, dim3(C_DIM / 128, M_ROWS / 128), dim3(256), 0, stream,
                     ah, wt_out, out, C_DIM, C_DIM);
}

// Round 16
// 166.038 us; speedup vs baseline: 1.2857x; 1.0424x over previous
//
#include <hip/hip_runtime.h>
#include <math.h>

#define T_SEQ 2048
#define C_DIM 1024
#define NHEAD 16
#define HDIM 64
#define M_ROWS 4096   // B*T
#define N_QKV 3072    // 3*C

typedef __attribute__((ext_vector_type(8))) short short8;   // 8 bf16 (4 VGPR)
typedef __attribute__((ext_vector_type(4))) float f32x4;    // MFMA C/D
typedef unsigned short ushort_t;

__device__ inline unsigned short f2bf(float x) {            // RNE f32->bf16
  union { float f; unsigned u; } v; v.f = x;
  unsigned r = v.u + 0x7FFF + ((v.u >> 16) & 1);
  return (unsigned short)(r >> 16);
}
__device__ inline float bf2f(unsigned short h) {
  union { unsigned u; float f; } v; v.u = ((unsigned)h) << 16; return v.f;
}
__device__ inline unsigned fbits(float x) {
  union { float f; unsigned u; } v; v.f = x; return v.u;
}

// async global->LDS, 16B per lane; LDS dest = wave-uniform base + lane*16
__device__ __forceinline__ void gll16(const char* g, char* l) {
  __builtin_amdgcn_global_load_lds(
      (const __attribute__((address_space(1))) unsigned*)g,
      (__attribute__((address_space(3))) unsigned*)l, 16, 0, 0);
}

// ---------------- fused abs-sum pass (both weights, one launch) -------------
__global__ __launch_bounds__(256) void abs2_k(const float* __restrict__ w_qkv,
                                              const float* __restrict__ w_out,
                                              float* __restrict__ part) {
  __shared__ float red[256];
  const int bx = blockIdx.x;
  const float* w;
  int n, nblk, bi;
  if (bx < 256) { w = w_qkv; n = N_QKV * C_DIM; nblk = 256; bi = bx; }
  else          { w = w_out; n = C_DIM * C_DIM; nblk = 128; bi = bx - 256; }
  float s = 0.f;
  for (int i = bi * 256 + threadIdx.x; i < n; i += nblk * 256)
    s += fabsf(w[i]);
  red[threadIdx.x] = s;
  __syncthreads();
  for (int st = 128; st > 0; st >>= 1) {
    if ((int)threadIdx.x < st) red[threadIdx.x] += red[threadIdx.x + st];
    __syncthreads();
  }
  if (threadIdx.x == 0) part[bx] = red[0];
}

__global__ __launch_bounds__(256) void finalize2_k(const float* __restrict__ part,
                                                   float* __restrict__ scales) {
  __shared__ float red[256];
  const int bx = blockIdx.x;
  const int lim = (bx == 0) ? 256 : 128;
  red[threadIdx.x] = ((int)threadIdx.x < lim) ? part[bx * 256 + threadIdx.x] : 0.f;
  __syncthreads();
  for (int st = 128; st > 0; st >>= 1) {
    if ((int)threadIdx.x < st) red[threadIdx.x] += red[threadIdx.x + st];
    __syncthreads();
  }
  if (threadIdx.x == 0) {
    float n = (bx == 0) ? (float)(N_QKV * C_DIM) : (float)(C_DIM * C_DIM);
    scales[bx] = fmaxf(red[0] / n, 1e-8f);
  }
}

// ---------------- fused elementwise: ternarize both weights + split x -------
__global__ __launch_bounds__(256) void prep_elem_k(const float* __restrict__ w_qkv,
                                                   const float* __restrict__ w_out,
                                                   const float* __restrict__ x,
                                                   ushort_t* __restrict__ wt_qkv,
                                                   ushort_t* __restrict__ wt_out,
                                                   ushort_t* __restrict__ xh,
                                                   ushort_t* __restrict__ xl,
                                                   const float* __restrict__ scales) {
  const int bx = blockIdx.x;
  if (bx < 12288) {
    const int i = bx * 256 + threadIdx.x;
    const float s = scales[0];
    const float t = rintf(w_qkv[i] / s);
    wt_qkv[i] = f2bf(fminf(1.f, fmaxf(-1.f, t)));
  } else if (bx < 16384) {
    const int i = (bx - 12288) * 256 + threadIdx.x;
    const float s = scales[1];
    const float t = rintf(w_out[i] / s);
    wt_out[i] = f2bf(fminf(1.f, fmaxf(-1.f, t)));
  } else {
    const int i = (bx - 16384) * 256 + threadIdx.x;     // float4 index
    const float4 v = ((const float4*)x)[i];
    const float vv[4] = {v.x, v.y, v.z, v.w};
    ushort_t hh[4], ll[4];
#pragma unroll
    for (int j = 0; j < 4; ++j) {
      hh[j] = f2bf(vv[j]);
      ll[j] = f2bf(vv[j] - bf2f(hh[j]));
    }
    ((ushort4*)xh)[i] = make_ushort4(hh[0], hh[1], hh[2], hh[3]);
    ((ushort4*)xl)[i] = make_ushort4(ll[0], ll[1], ll[2], ll[3]);
  }
}

// ---------------- fused qkv GEMM: hi/lo MFMA + direct img epilogue ----------
// Loop identical to gemm_bf16_hl (branch-free). Epilogue routes per-block:
// Q tiles -> fp32 qG [4096][1024]; K tiles -> img khi/klo; V tiles -> img vT.
// Swizzle formulas are element-exact matches of the old prep_kv writes.
__global__ __launch_bounds__(256) void gemm_qkv_k(const ushort_t* __restrict__ Ah,
                                                  const ushort_t* __restrict__ Al,
                                                  const ushort_t* __restrict__ Bw,
                                                  float* __restrict__ qG,
                                                  char* __restrict__ img,
                                                  int Kd) {
  __shared__ __align__(16) char lds[49152];   // Ah 16K | Al 16K | B 16K
  const int tid = threadIdx.x;
  const int bm = blockIdx.y << 7, bn = blockIdx.x << 7;
  const int w = tid >> 6, lane = tid & 63;
  const int wm = (w >> 1) << 6, wn = (w & 1) << 6;
  const int fr = lane & 15, fc = lane >> 4;

  int srow[4], scol[4];
#pragma unroll
  for (int i = 0; i < 4; ++i) {
    const int slot = i * 256 + tid;
    const int r = slot >> 3, s = slot & 7;
    srow[i] = r;
    scol[i] = (s ^ (r & 7)) << 3;            // pre-swizzled source column
  }

  f32x4 acc[4][4];
  const f32x4 z = {0.f, 0.f, 0.f, 0.f};
#pragma unroll
  for (int i = 0; i < 4; ++i)
#pragma unroll
    for (int j = 0; j < 4; ++j) acc[i][j] = z;

  for (int k0 = 0; k0 < Kd; k0 += 64) {
    __syncthreads();
#pragma unroll
    for (int i = 0; i < 4; ++i) {
      const int d16 = (i * 256 + tid) * 16;
      const size_t ga = (size_t)(bm + srow[i]) * Kd + k0 + scol[i];
      const size_t gb = (size_t)(bn + srow[i]) * Kd + k0 + scol[i];
      gll16((const char*)(Ah + ga), lds + d16);
      gll16((const char*)(Al + ga), lds + 16384 + d16);
      gll16((const char*)(Bw + gb), lds + 32768 + d16);
    }
    __syncthreads();
#pragma unroll
    for (int ks = 0; ks < 2; ++ks) {
      short8 af[4], lf[4], bf[4];
#pragma unroll
      for (int i = 0; i < 4; ++i) {
        const int ra = wm + i * 16 + fr;
        const int ca = (ks * 64 + fc * 16) ^ ((ra & 7) << 4);
        af[i] = *(const short8*)(lds + ra * 128 + ca);
        lf[i] = *(const short8*)(lds + 16384 + ra * 128 + ca);
        const int rb = wn + i * 16 + fr;
        const int cbb = (ks * 64 + fc * 16) ^ ((rb & 7) << 4);
        bf[i] = *(const short8*)(lds + 32768 + rb * 128 + cbb);
      }
#pragma unroll
      for (int i = 0; i < 4; ++i)
#pragma unroll
        for (int j = 0; j < 4; ++j) {
          acc[i][j] = __builtin_amdgcn_mfma_f32_16x16x32_bf16(af[i], bf[j], acc[i][j], 0, 0, 0);
          acc[i][j] = __builtin_amdgcn_mfma_f32_16x16x32_bf16(lf[i], bf[j], acc[i][j], 0, 0, 0);
        }
    }
  }

  // ---- epilogue (block-uniform routing on bn) ----
  if (bn < 1024) {
    // Q: fp32 [4096][1024]
#pragma unroll
    for (int i = 0; i < 4; ++i)
#pragma unroll
      for (int j = 0; j < 4; ++j) {
        float* cp = qG + (size_t)(bm + wm + i * 16 + fc * 4) * 1024 + bn + wn + j * 16 + fr;
#pragma unroll
        for (int r = 0; r < 4; ++r) cp[(size_t)r * 1024] = acc[i][j][r];
      }
  } else if (bn < 2048) {
    // K -> img hi/lo: off = key*128 + ((d*2)^((key&7)<<4))
#pragma unroll
    for (int i = 0; i < 4; ++i) {
      const int row0 = bm + wm + i * 16 + fc * 4;
#pragma unroll
      for (int r = 0; r < 4; ++r) {
        const int row = row0 + r;
        const int bb = row >> 11, t = row & 2047;
        const int c = t >> 6, key = t & 63;
        const int ksw = (key & 7) << 4;
        char* const igb = img + ((size_t)(bb << 4) * 32) * 24576 + (size_t)c * 24576 + key * 128;
#pragma unroll
        for (int j = 0; j < 4; ++j) {
          const int col = bn + wn + j * 16 + fr - 1024;
          const int h = col >> 6, d = col & 63;
          char* const ig = igb + (size_t)(h * 32) * 24576;
          const float v = acc[i][j][r];
          const unsigned short hi = f2bf(v);
          const unsigned short lo = f2bf(v - bf2f(hi));
          const int off = (d * 2) ^ ksw;
          *(ushort_t*)(ig + off) = hi;
          *(ushort_t*)(ig + 8192 + off) = lo;
        }
      }
    }
  } else {
    // V -> img vT: off = 16384 + d*128 + ((key*2)^((d&7)<<4))
#pragma unroll
    for (int i = 0; i < 4; ++i) {
      const int row0 = bm + wm + i * 16 + fc * 4;
#pragma unroll
      for (int r = 0; r < 4; ++r) {
        const int row = row0 + r;
        const int bb = row >> 11, t = row & 2047;
        const int c = t >> 6, key = t & 63;
        char* const igb = img + ((size_t)(bb << 4) * 32) * 24576 + (size_t)c * 24576 + 16384;
#pragma unroll
        for (int j = 0; j < 4; ++j) {
          const int col = bn + wn + j * 16 + fr - 2048;
          const int h = col >> 6, d = col & 63;
          char* const ig = igb + (size_t)(h * 32) * 24576;
          const int off = d * 128 + ((key * 2) ^ ((d & 7) << 4));
          *(ushort_t*)(ig + off) = f2bf(acc[i][j][r]);
        }
      }
    }
  }
}

// ---------------- bf16 MFMA GEMM, single-pass A (out projection) ------------
__global__ __launch_bounds__(256) void gemm_bf16(const ushort_t* __restrict__ A,
                                                 const ushort_t* __restrict__ Bw,
                                                 float* __restrict__ C,
                                                 int Nd, int Kd) {
  __shared__ __align__(16) char lds[32768];   // A 16K | B 16K
  const int tid = threadIdx.x;
  const int bm = blockIdx.y << 7, bn = blockIdx.x << 7;
  const int w = tid >> 6, lane = tid & 63;
  const int wm = (w >> 1) << 6, wn = (w & 1) << 6;
  const int fr = lane & 15, fc = lane >> 4;

  int srow[4], scol[4];
#pragma unroll
  for (int i = 0; i < 4; ++i) {
    const int slot = i * 256 + tid;
    const int r = slot >> 3, s = slot & 7;
    srow[i] = r;
    scol[i] = (s ^ (r & 7)) << 3;
  }

  f32x4 acc[4][4];
  const f32x4 z = {0.f, 0.f, 0.f, 0.f};
#pragma unroll
  for (int i = 0; i < 4; ++i)
#pragma unroll
    for (int j = 0; j < 4; ++j) acc[i][j] = z;

  for (int k0 = 0; k0 < Kd; k0 += 64) {
    __syncthreads();
#pragma unroll
    for (int i = 0; i < 4; ++i) {
      const int d16 = (i * 256 + tid) * 16;
      gll16((const char*)(A + (size_t)(bm + srow[i]) * Kd + k0 + scol[i]), lds + d16);
      gll16((const char*)(Bw + (size_t)(bn + srow[i]) * Kd + k0 + scol[i]), lds + 16384 + d16);
    }
    __syncthreads();
#pragma unroll
    for (int ks = 0; ks < 2; ++ks) {
      short8 af[4], bf[4];
#pragma unroll
      for (int i = 0; i < 4; ++i) {
        const int ra = wm + i * 16 + fr;
        af[i] = *(const short8*)(lds + ra * 128 + ((ks * 64 + fc * 16) ^ ((ra & 7) << 4)));
        const int rb = wn + i * 16 + fr;
        bf[i] = *(const short8*)(lds + 16384 + rb * 128 + ((ks * 64 + fc * 16) ^ ((rb & 7) << 4)));
      }
#pragma unroll
      for (int i = 0; i < 4; ++i)
#pragma unroll
        for (int j = 0; j < 4; ++j)
          acc[i][j] = __builtin_amdgcn_mfma_f32_16x16x32_bf16(af[i], bf[j], acc[i][j], 0, 0, 0);
    }
  }
#pragma unroll
  for (int i = 0; i < 4; ++i)
#pragma unroll
    for (int j = 0; j < 4; ++j) {
      float* cp = C + (size_t)(bm + wm + i * 16 + fc * 4) * Nd + bn + wn + j * 16 + fr;
#pragma unroll
      for (int r = 0; r < 4; ++r) cp[(size_t)r * Nd] = acc[i][j][r];
    }
}

// ---------------- swapped-QK single-tile attention, single-buffered ---------
struct TS2 { f32x4 O[4]; float m; float l; };

__device__ __forceinline__ void post_qk(f32x4* s4, TS2& st, const char* vTp,
                                        const bool diag, const int w, const int lg,
                                        const int lr, const int sh0, const int sh1) {
  if (diag) {
#pragma unroll
    for (int f = 0; f < 4; ++f)
#pragma unroll
      for (int r = 0; r < 4; ++r)
        if (16 * f + 4 * lg + r > w * 16 + lr) s4[f][r] = -1e30f;
  }
  float mc = fmaxf(fmaxf(s4[0][0], s4[0][1]), fmaxf(s4[0][2], s4[0][3]));
#pragma unroll
  for (int f = 1; f < 4; ++f)
#pragma unroll
    for (int r = 0; r < 4; ++r) mc = fmaxf(mc, s4[f][r]);
  if (__any(mc > st.m + 11.5f)) {          // defer-max (log2 units)
    mc = fmaxf(mc, __shfl_xor(mc, 16));
    mc = fmaxf(mc, __shfl_xor(mc, 32));
    const float mn = fmaxf(st.m, mc);
    const float rs = exp2f(st.m - mn);
    st.m = mn;
    st.l *= rs;
#pragma unroll
    for (int n = 0; n < 4; ++n)
#pragma unroll
      for (int r = 0; r < 4; ++r) st.O[n][r] *= rs;
  }
#pragma unroll
  for (int f = 0; f < 4; ++f)
#pragma unroll
    for (int r = 0; r < 4; ++r) s4[f][r] = exp2f(s4[f][r] - st.m);
#pragma unroll
  for (int f = 0; f < 4; ++f)
    st.l += (s4[f][0] + s4[f][1]) + (s4[f][2] + s4[f][3]);

  // pack adjacent key-pairs: D[f][rp] = bf16(p[2rp]) | bf16(p[2rp+1])<<16
  unsigned D[4][2];
#pragma unroll
  for (int f = 0; f < 4; ++f)
#pragma unroll
    for (int rp = 0; rp < 2; ++rp)
      D[f][rp] = (fbits(s4[f][2 * rp + 1]) & 0xFFFF0000u) | (fbits(s4[f][2 * rp]) >> 16);

  // gather group's P into B-operand order
  int g[4][2][2];
#pragma unroll
  for (int f = 0; f < 4; ++f)
#pragma unroll
    for (int rp = 0; rp < 2; ++rp) {
      g[f][rp][0] = __shfl((int)D[f][rp], sh0, 64);
      g[f][rp][1] = __shfl((int)D[f][rp], sh1, 64);
    }
  const bool hi2 = (lg & 2) != 0;
  union PB { int4 i; short8 s; } pb0, pb1;
  pb0.i.x = hi2 ? g[1][0][0] : g[0][0][0];
  pb0.i.y = hi2 ? g[1][1][0] : g[0][1][0];
  pb0.i.z = hi2 ? g[1][0][1] : g[0][0][1];
  pb0.i.w = hi2 ? g[1][1][1] : g[0][1][1];
  pb1.i.x = hi2 ? g[3][0][0] : g[2][0][0];
  pb1.i.y = hi2 ? g[3][1][0] : g[2][1][0];
  pb1.i.z = hi2 ? g[3][0][1] : g[2][0][1];
  pb1.i.w = hi2 ? g[3][1][1] : g[2][1][1];

  // PV: O^T[d][q] = mfma(A=V^T rows 16n+lr, B=P^T)
  const int swz = (lr & 7) << 4;
#pragma unroll
  for (int n = 0; n < 4; ++n) {
    const int d = 16 * n + lr;
    const short8 va0 = *(const short8*)(vTp + d * 128 + ((lg * 16) ^ swz));
    st.O[n] = __builtin_amdgcn_mfma_f32_16x16x32_bf16(va0, pb0.s, st.O[n], 0, 0, 0);
    const short8 va1 = *(const short8*)(vTp + d * 128 + ((64 + lg * 16) ^ swz));
    st.O[n] = __builtin_amdgcn_mfma_f32_16x16x32_bf16(va1, pb1.s, st.O[n], 0, 0, 0);
  }
}

__device__ __forceinline__ void load_q(const float* qG, int b, int qt, int h,
                                       int w, int lg, int lr,
                                       short8* qh, short8* ql) {
  const float* qrow = qG + (size_t)(b * T_SEQ + qt * 64 + w * 16 + lr) * 1024 + (h << 6);
#pragma unroll
  for (int s = 0; s < 2; ++s) {
    const float4 a0 = *(const float4*)(qrow + s * 32 + lg * 8);
    const float4 a1 = *(const float4*)(qrow + s * 32 + lg * 8 + 4);
    const float xv[8] = {a0.x, a0.y, a0.z, a0.w, a1.x, a1.y, a1.z, a1.w};
#pragma unroll
    for (int j = 0; j < 8; ++j) {
      const float xs = xv[j] * 0.1803368801f;   // (1/8) * log2(e): exp2 domain
      const unsigned short hs = f2bf(xs);
      qh[s][j] = (short)hs;
      ql[s][j] = (short)f2bf(xs - bf2f(hs));
    }
  }
}

__device__ __forceinline__ void store_o3(ushort_t* oh, TS2& st,
                                         int b, int qt, int h,
                                         int w, int lg, int lr) {
  float l = st.l;
  l += __shfl_xor(l, 16);
  l += __shfl_xor(l, 32);
  const float inv = 1.f / l;
  ushort_t* orow = oh + (size_t)(b * T_SEQ + qt * 64 + w * 16 + lr) * C_DIM
                   + (h << 6) + (lg << 2);
#pragma unroll
  for (int n = 0; n < 4; ++n) {
    ushort4 o;
    o.x = f2bf(st.O[n][0] * inv);
    o.y = f2bf(st.O[n][1] * inv);
    o.z = f2bf(st.O[n][2] * inv);
    o.w = f2bf(st.O[n][3] * inv);
    *(ushort4*)(orow + 16 * n) = o;        // d = 16n + 4lg + r
  }
}

__global__ __launch_bounds__(256) void attn1_k(const float* __restrict__ qG,
                                               const char* __restrict__ img,
                                               ushort_t* __restrict__ oh) {
  __shared__ __align__(16) char smem[24576];   // single chunk image
  const int tid  = threadIdx.x;
  const int lane = tid & 63;
  const int w    = tid >> 6;
  const int lg   = lane >> 4;
  const int lr   = lane & 15;
  const int sh0  = lr + 32 * (lg & 1);     // P-gather source lanes
  const int sh1  = sh0 + 16;

  // gg in low 5 bits (XCD-pinned img slice); qt descending (LPT balance)
  const int bx = blockIdx.x;
  const int gg = bx & 31;
  const int qt = 31 - (bx >> 5);
  const int h  = gg & 15, b = gg >> 4;

  const char* img_gg = img + (size_t)gg * 32 * 24576;

  short8 qh[2], ql[2];
  load_q(qG, b, qt, h, w, lg, lr, qh, ql);

  TS2 st;
#pragma unroll
  for (int n = 0; n < 4; ++n) {
    const f32x4 z = {0.f, 0.f, 0.f, 0.f};
    st.O[n] = z;
  }
  st.m = -1e30f;
  st.l = 0.f;

  for (int c = 0; c <= qt; ++c) {
    __syncthreads();                         // prev compute done (noop at c=0)
    const char* src = img_gg + (size_t)c * 24576;
#pragma unroll
    for (int i = 0; i < 6; ++i)
      gll16(src + i * 4096 + tid * 16, smem + i * 4096 + tid * 16);
    __syncthreads();                         // vmcnt drained -> image ready

    const char* khp = smem;
    const char* klp = smem + 8192;
    const char* vTp = smem + 16384;

    // ---- swapped QK: S^T = mfma(K, Q) ----
    f32x4 s4[4];
    const f32x4 z = {0.f, 0.f, 0.f, 0.f};
#pragma unroll
    for (int f = 0; f < 4; ++f) s4[f] = z;
#pragma unroll
    for (int s = 0; s < 2; ++s) {
      const int cb = s * 64 + lg * 16;
#pragma unroll
      for (int f = 0; f < 4; ++f) {
        const int row = lr + 16 * f;
        const int byt = row * 128 + (cb ^ ((row & 7) << 4));
        const short8 kh8 = *(const short8*)(khp + byt);
        const short8 kl8 = *(const short8*)(klp + byt);
        s4[f] = __builtin_amdgcn_mfma_f32_16x16x32_bf16(kh8, qh[s], s4[f], 0, 0, 0);
        s4[f] = __builtin_amdgcn_mfma_f32_16x16x32_bf16(kh8, ql[s], s4[f], 0, 0, 0);
        s4[f] = __builtin_amdgcn_mfma_f32_16x16x32_bf16(kl8, qh[s], s4[f], 0, 0, 0);
      }
    }
    post_qk(s4, st, vTp, c == qt, w, lg, lr, sh0, sh1);
  }

  store_o3(oh, st, b, qt, h, w, lg, lr);
}

// ---------------- launch ----------------------------------------------------
extern "C" void kernel_launch(void* const* d_in, const int* in_sizes, int n_in,
                              void* d_out, int out_size, void* d_ws, size_t ws_size,
                              hipStream_t stream) {
  const float* x      = (const float*)d_in[0];   // [4096][1024]
  const float* w_qkv  = (const float*)d_in[1];   // [3072][1024]
  const float* w_out  = (const float*)d_in[2];   // [1024][1024]
  float* out = (float*)d_out;                    // [4096][1024]

  // layout (no aliasing: gemm_qkv writes img while reading wt_qkv)
  char* pch = (char*)d_ws;
  ushort_t* wt_out = (ushort_t*)pch;  pch += (size_t)C_DIM * C_DIM * 2;    // 2MB
  ushort_t* xh     = (ushort_t*)pch;  pch += (size_t)M_ROWS * C_DIM * 2;   // 8MB
  ushort_t* xl     = (ushort_t*)pch;  pch += (size_t)M_ROWS * C_DIM * 2;   // 8MB
  float*    qG     = (float*)pch;     pch += (size_t)M_ROWS * C_DIM * 4;   // 16MB
  ushort_t* wt_qkv = (ushort_t*)pch;  pch += (size_t)N_QKV * C_DIM * 2;    // 6.3MB
  char*     img    = pch;             pch += (size_t)1024 * 24576;         // 25.2MB
  float*    part   = (float*)pch;     pch += 512 * 4;
  float*    scales = (float*)pch;
  ushort_t* ah = xh;   // x hi dead after gemm1 -> attn output

  hipLaunchKernelGGL(abs2_k, dim3(384), dim3(256), 0, stream, w_qkv, w_out, part);
  hipLaunchKernelGGL(finalize2_k, dim3(2), dim3(256), 0, stream, part, scales);

  hipLaunchKernelGGL(prep_elem_k, dim3(20480), dim3(256), 0, stream,
                     w_qkv, w_out, x, wt_qkv, wt_out, xh, xl, scales);

  // fused qkv GEMM: Q -> qG fp32; K/V -> img bf16 (prep_kv folded in)
  hipLaunchKernelGGL(gemm_qkv_k, dim3(N_QKV / 128, M_ROWS / 128), dim3(256), 0, stream,
                     xh, xl, wt_qkv, qG, img, C_DIM);

  // attention -> bf16 (single-tile, single-buffer 24KB, LPT order)
  hipLaunchKernelGGL(attn1_k, dim3(1024), dim3(256), 0, stream, qG, img, ah);

  // out = ah @ wt_out^T
  hipLaunchKernelGGL(gemm_bf16, dim3(C_DIM / 128, M_ROWS / 128), dim3(256), 0, stream,
                     ah, wt_out, out, C_DIM, C_DIM);
}